// Round 4
// baseline (983.357 us; speedup 1.0000x reference)
//
#include <hip/hip_runtime.h>
#include <hip/hip_bf16.h>
#include <stdint.h>

// PairEnergies GNN on MI355X — round 10.
// r9 with the spill fix: __launch_bounds__(256,1) on gc (the (256,2) bound
// capped arch VGPRs at 128 -> ~85MB scratch traffic per dispatch, WRITE_SIZE
// 101MB vs 15.7MB legit). LDS (80KB) still limits occupancy to 2 blocks/CU,
// and <=256 VGPR keeps 8 waves/CU, so no occupancy loss. Also: Abuf re-zero
// folded into node_ln_kernel (zero once up front).

typedef __bf16 bf16_t;
typedef __attribute__((ext_vector_type(8))) __bf16 bf16x8;
typedef __attribute__((ext_vector_type(4))) float f32x4;

#define B_    2
#define N_    1024
#define KN    30
#define H_    128
#define L_    3
#define ODIM_ 400
#define NK    (N_ * KN)        // 30720
#define RT    (B_ * N_ * KN)   // 61440
#define BN_   (B_ * N_)        // 2048

#define EPI_PLAIN 0
#define EPI_RELU  1
#define EPI_F32   2
#define EPI_ADDUG 3
#define EPI_LN    4
#define EPI_OUT   5

__device__ __forceinline__ float wred(float v) {
#pragma unroll
  for (int off = 32; off > 0; off >>= 1) v += __shfl_xor(v, off, 64);
  return v;
}

// async global->LDS, 16B per lane; lds base must be wave-uniform.
__device__ __forceinline__ void gld16(const bf16_t* g, bf16_t* l) {
  __builtin_amdgcn_global_load_lds(
      (__attribute__((address_space(1))) void*)(g),
      (__attribute__((address_space(3))) void*)(l), 16, 0, 0);
}

// raw barrier (no vmcnt drain). sched_barrier fences compiler motion.
__device__ __forceinline__ void bar() {
  __builtin_amdgcn_sched_barrier(0);
  __builtin_amdgcn_s_barrier();
  __builtin_amdgcn_sched_barrier(0);
}
// barrier with LDS-op completion (ds_write visibility across waves)
__device__ __forceinline__ void barL() {
  asm volatile("s_waitcnt lgkmcnt(0)" ::: "memory");
  __builtin_amdgcn_s_barrier();
  __builtin_amdgcn_sched_barrier(0);
}

// one BK=64 round of 128x128 MFMA on swizzled LDS halves
__device__ __forceinline__ void mm64(const bf16_t* __restrict__ Ah,
                                     const bf16_t* __restrict__ Bh,
                                     int wm, int wn, int fm, int q, int fx,
                                     f32x4 (&acc)[4][4])
{
#pragma unroll
  for (int h = 0; h < 2; ++h) {
    bf16x8 af[4], bfv[4];
#pragma unroll
    for (int mi = 0; mi < 4; ++mi)
      af[mi] = *reinterpret_cast<const bf16x8*>(
          &Ah[(wm * 64 + mi * 16 + fm) * 64 + ((((h << 2) | q) ^ fx) << 3)]);
#pragma unroll
    for (int ni = 0; ni < 4; ++ni)
      bfv[ni] = *reinterpret_cast<const bf16x8*>(
          &Bh[(wn * 64 + ni * 16 + fm) * 64 + ((((h << 2) | q) ^ fx) << 3)]);
#pragma unroll
    for (int mi = 0; mi < 4; ++mi)
#pragma unroll
      for (int ni = 0; ni < 4; ++ni)
        acc[mi][ni] = __builtin_amdgcn_mfma_f32_16x16x32_bf16(
            af[mi], bfv[ni], acc[mi][ni], 0, 0, 0);
  }
}

// ================= fused chain kernel =================
struct GCArgs {
  const bf16_t* Ain;
  const bf16_t* W1; int koff1; int ldw1;
  const bf16_t* W2; const bf16_t* b2;
  const bf16_t* W3; const bf16_t* b3;
  const float* U; const float* G; const int* E;
  const float* ma;          // mask_attend (MODE0 scale)
  float* Agg;               // MODE0: atomic node accumulator [BN_*128]
  const bf16_t* Wd1; const bf16_t* bd1;
  const bf16_t* Wd2; const bf16_t* bd2;
  const float* mvec;        // final-LN row mask: ma (MODE1) / xmf (MODE2)
  bf16_t* outF;             // hE (MODE1) / hV (MODE2)
  const bf16_t* Wug; const bf16_t* bug;  // MODE2: W1e, eb1c for U/G emit
  float* Uo; float* Go;
};

template<int MODE>
__global__ __launch_bounds__(256, 1) void gc(GCArgs a)
{
  __shared__ __align__(16) bf16_t bufA[2][8192];   // 32 KB
  __shared__ __align__(16) bf16_t bufB[2][8192];   // 32 KB
  __shared__ __align__(16) bf16_t Ws[8192];        // 16 KB weights / LN / agg
  float* lnS  = (float*)Ws;
  float* lnS2 = lnS + 256;
  float* aggS = (float*)Ws;                        // MODE0: [6][128]

  const int tid = threadIdx.x;
  const int w = tid >> 6, l = tid & 63;
  const int wm = w & 1, wn = w >> 1;
  const int row0 = blockIdx.x * 128;
  const int lr = l >> 3;
  const int kg8 = ((l & 7) ^ lr) << 3;   // swizzled source granule (elems)
  const int fm = l & 15, q = l >> 4, fx = fm & 7;
  const int r4 = w * 32 + lr;

  bf16x8 R[4];   // prefetched weight tile slice (4 rows x 16B per thread)

  auto wload = [&](const bf16_t* W, int ldw, int koff) {
    const bf16_t* gb = W + (size_t)r4 * ldw + koff + kg8;
#pragma unroll
    for (int s = 0; s < 4; ++s)
      R[s] = *reinterpret_cast<const bf16x8*>(gb + (size_t)(s * 8) * ldw);
  };

  // one kt-step: commit prefetched R -> Ws, prefetch (Wn,ldwn,koffn) -> R,
  // sync, MFMA on (SRC x Ws). No vmcnt drain anywhere.
  auto kt_step = [&](const bf16_t* Wn, int ldwn, int koffn,
                     const bf16_t* SRC, f32x4 (&acc)[4][4]) {
    bar();                               // prev Ws readers done (by arrival)
#pragma unroll
    for (int s = 0; s < 4; ++s)
      *reinterpret_cast<bf16x8*>(&Ws[w * 2048 + s * 512 + l * 8]) = R[s];
    wload(Wn, ldwn, koffn);              // in flight across this MFMA
    asm volatile("s_waitcnt lgkmcnt(0)" ::: "memory");
    __builtin_amdgcn_s_barrier();
    __builtin_amdgcn_sched_barrier(0);
    mm64(SRC, Ws, wm, wn, fm, q, fx, acc);
  };

  auto wb = [&](f32x4 (&acc)[4][4], bf16_t* dst) {
#pragma unroll
    for (int mi = 0; mi < 4; ++mi)
#pragma unroll
      for (int rr = 0; rr < 4; ++rr) {
        int row = wm * 64 + mi * 16 + q * 4 + rr;
#pragma unroll
        for (int ni = 0; ni < 4; ++ni) {
          int cl = ni * 16 + fm;
          dst[wn * 8192 + row * 64 +
              ((((cl >> 3) ^ (row & 7)) << 3) | (cl & 7))] =
              (bf16_t)acc[mi][ni][rr];
        }
      }
  };

  // ---- stage activation tile + first weight prefetch ----
  if constexpr (MODE <= 1) wload(a.W1, a.ldw1, a.koff1);
  else                     wload(a.Wd1, 128, 0);
  {
    bf16_t* dst = (MODE == 2) ? bufB[0] : bufA[0];
    const bf16_t* gb = a.Ain + (size_t)(row0 + r4) * 128 + kg8;
#pragma unroll
    for (int kt = 0; kt < 2; ++kt)
#pragma unroll
      for (int s = 0; s < 4; ++s)
        gld16(gb + (size_t)(s * 8) * 128 + kt * 64,
              dst + kt * 8192 + w * 2048 + s * 512);
  }
  __syncthreads();   // one full drain per chain (activation DMA + R loads)

  if constexpr (MODE <= 1) {
    // ---- S1: m1 = relu(A @ W1(koff) + U + G) -> bufB ----
    f32x4 acc1[4][4] = {};
    kt_step(a.W1, a.ldw1, a.koff1 + 64, bufA[0], acc1);
    kt_step(a.W2, 128, 0,               bufA[0] + 8192, acc1);
#pragma unroll
    for (int mi = 0; mi < 4; ++mi)
#pragma unroll
      for (int rr = 0; rr < 4; ++rr) {
        int rg = row0 + wm * 64 + mi * 16 + q * 4 + rr;
        const float* Ur = a.U + (size_t)(rg / KN) * 128;
        const float* Gr = a.G + (size_t)((rg / NK) * N_ + a.E[rg]) * 128;
#pragma unroll
        for (int ni = 0; ni < 4; ++ni) {
          int col = wn * 64 + ni * 16 + fm;
          acc1[mi][ni][rr] = fmaxf(acc1[mi][ni][rr] + Ur[col] + Gr[col], 0.f);
        }
      }
    wb(acc1, bufB[0]);

    // ---- S2: m2 = relu(m1 @ W2 + b2) -> bufB (after barrier) ----
    f32x4 acc2[4][4] = {};
    kt_step(a.W2, 128, 64, bufB[0], acc2);
    kt_step(a.W3, 128, 0,  bufB[0] + 8192, acc2);
#pragma unroll
    for (int mi = 0; mi < 4; ++mi)
#pragma unroll
      for (int rr = 0; rr < 4; ++rr)
#pragma unroll
        for (int ni = 0; ni < 4; ++ni) {
          int col = wn * 64 + ni * 16 + fm;
          acc2[mi][ni][rr] = fmaxf(acc2[mi][ni][rr] + (float)a.b2[col], 0.f);
        }
    bar();             // all waves done reading m1 from bufB
    wb(acc2, bufB[0]);

    // ---- S3: m3 = m2 @ W3 ----
    f32x4 acc3[4][4] = {};
    kt_step(a.W3, 128, 64, bufB[0], acc3);
    if constexpr (MODE == 0)
      kt_step(a.W3, 128, 64, bufB[0] + 8192, acc3);     // dummy prefetch
    else
      kt_step(a.Wd1, 128, 0, bufB[0] + 8192, acc3);     // prefetch FFN c0 kt0

    if constexpr (MODE == 0) {
      // node aggregation: aggS[node_local][col] += (m3+b3)*ma, then global
      bar();                                   // Ws free
      for (int i = tid; i < 768; i += 256) aggS[i] = 0.f;
      barL();
      const int nb0 = row0 / KN;
#pragma unroll
      for (int mi = 0; mi < 4; ++mi)
#pragma unroll
        for (int rr = 0; rr < 4; ++rr) {
          int rg = row0 + wm * 64 + mi * 16 + q * 4 + rr;
          float mav = a.ma[rg];
          int nl = rg / KN - nb0;
#pragma unroll
          for (int ni = 0; ni < 4; ++ni) {
            int col = wn * 64 + ni * 16 + fm;
            atomicAdd(&aggS[nl * 128 + col],
                      (acc3[mi][ni][rr] + (float)a.b3[col]) * mav);
          }
        }
      barL();
      const int nbL = (row0 + 127) / KN;
      for (int i = tid; i < 768; i += 256) {
        int ng = nb0 + (i >> 7);
        if (ng <= nbL)
          atomicAdd(&a.Agg[(size_t)ng * 128 + (i & 127)], aggS[i]);
      }
      return;
    } else {
      // S3-LN: X = LN(hE(bufA) + m3 + b3) -> bufB
      bar();           // Ws->lnS reuse safe; bufB m2 reads done
#pragma unroll
      for (int mi = 0; mi < 4; ++mi)
#pragma unroll
        for (int rr = 0; rr < 4; ++rr) {
          int lrow = wm * 64 + mi * 16 + q * 4 + rr;
          float s = 0.f, s2 = 0.f;
#pragma unroll
          for (int ni = 0; ni < 4; ++ni) {
            int cl = ni * 16 + fm;
            float rv = (float)bufA[wn][lrow * 64 +
                ((((cl >> 3) ^ (lrow & 7)) << 3) | (cl & 7))];
            float v = acc3[mi][ni][rr] + (float)a.b3[wn * 64 + cl] + rv;
            acc3[mi][ni][rr] = v;
            s += v; s2 += v * v;
          }
#pragma unroll
          for (int d = 1; d < 16; d <<= 1) {
            s += __shfl_xor(s, d, 64); s2 += __shfl_xor(s2, d, 64);
          }
          if (fm == (mi * 4 + rr)) { lnS[wn * 128 + lrow] = s;
                                     lnS2[wn * 128 + lrow] = s2; }
        }
      barL();
#pragma unroll
      for (int mi = 0; mi < 4; ++mi)
#pragma unroll
        for (int rr = 0; rr < 4; ++rr) {
          int lrow = wm * 64 + mi * 16 + q * 4 + rr;
          float st = lnS[lrow] + lnS[128 + lrow];
          float st2 = lnS2[lrow] + lnS2[128 + lrow];
          float mu = st * (1.f / 128.f);
          float var = fmaxf(st2 * (1.f / 128.f) - mu * mu, 0.f);
          float rstd = rsqrtf(var + 1e-5f);
#pragma unroll
          for (int ni = 0; ni < 4; ++ni) {
            int cl = ni * 16 + fm;
            bufB[wn][lrow * 64 +
                ((((cl >> 3) ^ (lrow & 7)) << 3) | (cl & 7))] =
                (bf16_t)((acc3[mi][ni][rr] - mu) * rstd);
          }
        }
    }
  }

  // ---- FFN: accF = sum_c relu(X @ Wd1_c + bd1_c) @ Wd2_c ; X in bufB ----
  {
    f32x4 accF[4][4] = {};
#pragma unroll 1
    for (int c = 0; c < 4; ++c) {
      const bf16_t* Wd1c = a.Wd1 + (size_t)c * 16384;
      f32x4 accH[4][4] = {};
      kt_step(Wd1c, 128, 64,      bufB[0], accH);
      kt_step(a.Wd2, 512, c * 128, bufB[0] + 8192, accH);
#pragma unroll
      for (int mi = 0; mi < 4; ++mi)
#pragma unroll
        for (int rr = 0; rr < 4; ++rr)
#pragma unroll
          for (int ni = 0; ni < 4; ++ni) {
            int col = wn * 64 + ni * 16 + fm;
            accH[mi][ni][rr] =
                fmaxf(accH[mi][ni][rr] + (float)a.bd1[c * 128 + col], 0.f);
          }
      wb(accH, bufA[0]);
      kt_step(a.Wd2, 512, c * 128 + 64, bufA[0], accF);
      const bf16_t* nxt; int nldw, nkoff;
      if (c < 3)            { nxt = a.Wd1 + (size_t)(c + 1) * 16384; nldw = 128; nkoff = 0; }
      else if (MODE == 2)   { nxt = a.Wug; nldw = 384; nkoff = 0; }
      else                  { nxt = a.Wd2; nldw = 512; nkoff = c * 128 + 64; }
      kt_step(nxt, nldw, nkoff, bufA[0] + 8192, accF);
    }

    // final LN: out = LN(X + accF + bd2) * mvec
    bar();
#pragma unroll
    for (int mi = 0; mi < 4; ++mi)
#pragma unroll
      for (int rr = 0; rr < 4; ++rr) {
        int lrow = wm * 64 + mi * 16 + q * 4 + rr;
        float s = 0.f, s2 = 0.f;
#pragma unroll
        for (int ni = 0; ni < 4; ++ni) {
          int cl = ni * 16 + fm;
          float xv = (float)bufB[wn][lrow * 64 +
              ((((cl >> 3) ^ (lrow & 7)) << 3) | (cl & 7))];
          float v = accF[mi][ni][rr] + (float)a.bd2[wn * 64 + cl] + xv;
          accF[mi][ni][rr] = v;
          s += v; s2 += v * v;
        }
#pragma unroll
        for (int d = 1; d < 16; d <<= 1) {
          s += __shfl_xor(s, d, 64); s2 += __shfl_xor(s2, d, 64);
        }
        if (fm == (mi * 4 + rr)) { lnS[wn * 128 + lrow] = s;
                                   lnS2[wn * 128 + lrow] = s2; }
      }
    barL();
#pragma unroll
    for (int mi = 0; mi < 4; ++mi)
#pragma unroll
      for (int rr = 0; rr < 4; ++rr) {
        int lrow = wm * 64 + mi * 16 + q * 4 + rr;
        size_t rg = (size_t)(row0 + lrow);
        float st = lnS[lrow] + lnS[128 + lrow];
        float st2 = lnS2[lrow] + lnS2[128 + lrow];
        float mu = st * (1.f / 128.f);
        float var = fmaxf(st2 * (1.f / 128.f) - mu * mu, 0.f);
        float rstd = rsqrtf(var + 1e-5f);
        float mk = a.mvec[rg];
#pragma unroll
        for (int ni = 0; ni < 4; ++ni) {
          int col = wn * 64 + ni * 16 + fm;
          float ov = (accF[mi][ni][rr] - mu) * rstd * mk;
          a.outF[rg * 128 + col] = (bf16_t)ov;
          if constexpr (MODE == 2) accF[mi][ni][rr] = ov;
        }
      }

    if constexpr (MODE == 2) {
      // emit edge-phase U/G from the fresh hV tile (kept in regs/LDS)
      bar();                       // all waves done reading X from bufB
      wb(accF, bufB[0]);           // hV_new -> bufB (swizzled)
      f32x4 accU[4][4] = {};
      kt_step(a.Wug, 384, 64,  bufB[0], accU);          // U kt0 (commit pre)
      kt_step(a.Wug, 384, 256, bufB[0] + 8192, accU);   // U kt1, pre G kt0
#pragma unroll
      for (int mi = 0; mi < 4; ++mi)
#pragma unroll
        for (int rr = 0; rr < 4; ++rr) {
          size_t rg = (size_t)(row0 + wm * 64 + mi * 16 + q * 4 + rr);
#pragma unroll
          for (int ni = 0; ni < 4; ++ni) {
            int col = wn * 64 + ni * 16 + fm;
            a.Uo[rg * 128 + col] = accU[mi][ni][rr] + (float)a.bug[col];
          }
        }
      f32x4 accG[4][4] = {};
      kt_step(a.Wug, 384, 320, bufB[0], accG);          // G kt0, pre G kt1
      kt_step(a.Wug, 384, 320, bufB[0] + 8192, accG);   // G kt1, dummy pre
#pragma unroll
      for (int mi = 0; mi < 4; ++mi)
#pragma unroll
        for (int rr = 0; rr < 4; ++rr) {
          size_t rg = (size_t)(row0 + wm * 64 + mi * 16 + q * 4 + rr);
#pragma unroll
          for (int ni = 0; ni < 4; ++ni) {
            int col = wn * 64 + ni * 16 + fm;
            a.Go[rg * 128 + col] = accG[mi][ni][rr];
          }
        }
    }
  }
}

// ================= unified 128x128 MFMA GEMM (embeds / head) ====
__global__ __launch_bounds__(256) void gk(
    const bf16_t* __restrict__ A, int lda,
    const bf16_t* __restrict__ Bt, int ldb, int koff,
    const bf16_t* __restrict__ bias,
    int N, int K, int epi,
    bf16_t* __restrict__ C,
    float* __restrict__ Cf, float* __restrict__ Cf1, int koff1,
    const float* __restrict__ U, const float* __restrict__ G,
    const int* __restrict__ E_idx,
    bf16_t* __restrict__ resid, const float* __restrict__ mvec, int row0g,
    const int* __restrict__ inv, const int* __restrict__ flag,
    void* __restrict__ outp)
{
  __shared__ __align__(16) bf16_t As[128 * 64];
  __shared__ __align__(16) bf16_t Bs[128 * 64];
  __shared__ float lnS[2][128];
  __shared__ float lnS2[2][128];

  float* CfD = Cf;
  if (epi == EPI_F32 && blockIdx.z == 1) { koff = koff1; bias = nullptr; CfD = Cf1; }

  const int tid = threadIdx.x;
  const int w = tid >> 6, l = tid & 63;
  const int wm = w & 1, wn = w >> 1;
  const int row0 = blockIdx.y * 128;
  const int col0 = blockIdx.x * 128;
  const int lr = l >> 3;
  const int kg8 = ((l & 7) ^ lr) << 3;

  const bf16_t* ap[4];
  const bf16_t* bp[4];
#pragma unroll
  for (int s = 0; s < 4; ++s) {
    int rA = row0 + w * 32 + s * 8 + lr;
    const bf16_t* abase;
    if (epi == EPI_OUT) {
      int bb = rA / NK;
      abase = A + (size_t)(bb * NK + inv[rA]) * lda;
    } else {
      abase = A + (size_t)rA * lda;
    }
    ap[s] = abase + kg8;
    int rB = col0 + w * 32 + s * 8 + lr;
    if (rB >= N) rB = N - 1;
    bp[s] = Bt + (size_t)rB * ldb + koff + kg8;
  }

  const int fm = l & 15, q = l >> 4, fx = fm & 7;
  f32x4 acc[4][4] = {};

  for (int kt = 0; kt < K; kt += 64) {
    __syncthreads();
#pragma unroll
    for (int s = 0; s < 4; ++s)
      gld16(ap[s] + kt, &As[w * 2048 + s * 512]);
#pragma unroll
    for (int s = 0; s < 4; ++s)
      gld16(bp[s] + kt, &Bs[w * 2048 + s * 512]);
    __syncthreads();
#pragma unroll
    for (int h = 0; h < 2; ++h) {
      bf16x8 af[4], bfv[4];
#pragma unroll
      for (int mi = 0; mi < 4; ++mi)
        af[mi] = *reinterpret_cast<const bf16x8*>(
            &As[(wm * 64 + mi * 16 + fm) * 64 + ((((h << 2) | q) ^ fx) << 3)]);
#pragma unroll
      for (int ni = 0; ni < 4; ++ni)
        bfv[ni] = *reinterpret_cast<const bf16x8*>(
            &Bs[(wn * 64 + ni * 16 + fm) * 64 + ((((h << 2) | q) ^ fx) << 3)]);
#pragma unroll
      for (int mi = 0; mi < 4; ++mi)
#pragma unroll
        for (int ni = 0; ni < 4; ++ni)
          acc[mi][ni] = __builtin_amdgcn_mfma_f32_16x16x32_bf16(
              af[mi], bfv[ni], acc[mi][ni], 0, 0, 0);
    }
  }

  if (epi <= EPI_F32) {
#pragma unroll
    for (int ni = 0; ni < 4; ++ni) {
      int col = col0 + wn * 64 + ni * 16 + fm;
      if (col >= N) continue;
      float bv = bias ? (float)bias[col] : 0.f;
#pragma unroll
      for (int mi = 0; mi < 4; ++mi)
#pragma unroll
        for (int rr = 0; rr < 4; ++rr) {
          size_t rg = (size_t)(row0g + row0 + wm * 64 + mi * 16 + q * 4 + rr);
          float v = acc[mi][ni][rr] + bv;
          if (epi == EPI_RELU) v = fmaxf(v, 0.f);
          if (epi == EPI_F32) CfD[rg * N + col] = v;
          else                C[rg * N + col] = (bf16_t)v;
        }
    }
  } else if (epi == EPI_LN) {
#pragma unroll
    for (int mi = 0; mi < 4; ++mi)
#pragma unroll
      for (int rr = 0; rr < 4; ++rr) {
        int lrow = wm * 64 + mi * 16 + q * 4 + rr;
        size_t rg = (size_t)(row0g + row0 + lrow);
        float s = 0.f, s2 = 0.f;
#pragma unroll
        for (int ni = 0; ni < 4; ++ni) {
          int col = wn * 64 + ni * 16 + fm;
          float v = acc[mi][ni][rr] + (bias ? (float)bias[col] : 0.f)
                    + (float)resid[rg * 128 + col];
          acc[mi][ni][rr] = v;
          s += v; s2 += v * v;
        }
#pragma unroll
        for (int d = 1; d < 16; d <<= 1) {
          s += __shfl_xor(s, d, 64); s2 += __shfl_xor(s2, d, 64);
        }
        if (fm == (mi * 4 + rr)) { lnS[wn][lrow] = s; lnS2[wn][lrow] = s2; }
      }
    __syncthreads();
#pragma unroll
    for (int mi = 0; mi < 4; ++mi)
#pragma unroll
      for (int rr = 0; rr < 4; ++rr) {
        int lrow = wm * 64 + mi * 16 + q * 4 + rr;
        size_t rg = (size_t)(row0g + row0 + lrow);
        float st = lnS[0][lrow] + lnS[1][lrow];
        float st2 = lnS2[0][lrow] + lnS2[1][lrow];
        float mu = st * (1.f / 128.f);
        float var = fmaxf(st2 * (1.f / 128.f) - mu * mu, 0.f);
        float rstd = rsqrtf(var + 1e-5f);
        float mk = mvec ? mvec[rg] : 1.f;
#pragma unroll
        for (int ni = 0; ni < 4; ++ni) {
          int col = wn * 64 + ni * 16 + fm;
          resid[rg * 128 + col] = (bf16_t)((acc[mi][ni][rr] - mu) * rstd * mk);
        }
      }
  } else if (epi == EPI_OUT) {
    const int fl = *flag;
#pragma unroll
    for (int ni = 0; ni < 4; ++ni) {
      int col = col0 + wn * 64 + ni * 16 + fm;
      if (col >= ODIM_) continue;
      float bv = bias ? (float)bias[col] : 0.f;
#pragma unroll
      for (int mi = 0; mi < 4; ++mi)
#pragma unroll
        for (int rr = 0; rr < 4; ++rr) {
          size_t rg = (size_t)(row0 + wm * 64 + mi * 16 + q * 4 + rr);
          float v = acc[mi][ni][rr] + bv;
          size_t idx = rg * ODIM_ + col;
          if (fl) ((bf16_t*)outp)[idx] = (bf16_t)v;
          else    ((float*)outp)[idx]  = v;
        }
    }
  }
}

// ================= dtype sniff =================
__global__ void flag_kernel(const uint32_t* __restrict__ xm_raw,
                            int* __restrict__ flag)
{
  if (threadIdx.x == 0 && blockIdx.x == 0)
    *flag = (xm_raw[0] == 0x3F803F80u) ? 1 : 0;
}

// ================= fused convert (+ weight transpose) =================
struct ConvSeg { const void* src; void* dst; int n; int K; int N; };
struct ConvArgs { ConvSeg s[29]; };

__global__ __launch_bounds__(256) void conv_kernel(
    ConvArgs a, int nseg, int total8, const int* __restrict__ flag)
{
  int t = blockIdx.x * 256 + threadIdx.x;
  if (t >= total8) return;
  const int fl = *flag;
  int seg = 0, t8 = t;
  while (seg < nseg - 1 && t8 >= (a.s[seg].n >> 3)) { t8 -= a.s[seg].n >> 3; ++seg; }
  const ConvSeg sg = a.s[seg];
  const int e = t8 << 3;
  float vals[8];
  if (fl) {
    union { uint4 v; bf16_t b[8]; } u;
    u.v = *((const uint4*)sg.src + t8);
#pragma unroll
    for (int j = 0; j < 8; ++j) vals[j] = (float)u.b[j];
  } else {
    const float* sp = (const float*)sg.src + e;
#pragma unroll
    for (int j = 0; j < 8; ++j) vals[j] = sp[j];
  }
  if (sg.N == 0) {
    union { uint4 v; bf16_t b[8]; } o;
#pragma unroll
    for (int j = 0; j < 8; ++j) o.b[j] = (bf16_t)vals[j];
    *((uint4*)sg.dst + t8) = o.v;
  } else {
    const int KN_ = sg.K * sg.N;
    const int lay = e / KN_;
    const int rem = e - lay * KN_;
    const int k = rem / sg.N;
    const int n0 = rem - k * sg.N;
    bf16_t* dp = (bf16_t*)sg.dst + (size_t)lay * KN_ + k;
#pragma unroll
    for (int j = 0; j < 8; ++j)
      dp[(size_t)(n0 + j) * sg.K] = (bf16_t)vals[j];
  }
}

// ================= mask_attend (+ float x_mask side copy) =================
__global__ __launch_bounds__(256) void mask_kernel(
    const bf16_t* __restrict__ xm, const int* __restrict__ E_idx,
    float* __restrict__ ma, float* __restrict__ xmf)
{
  int r = blockIdx.x * 256 + threadIdx.x;
  if (r >= RT) return;
  if (r < BN_) xmf[r] = (float)xm[r];
  int b = r / NK;
  int n = (r / KN) % N_;
  ma[r] = (float)xm[b * N_ + E_idx[r]] * (float)xm[b * N_ + n];
}

// ================= zero + node LN =================
__global__ __launch_bounds__(256) void zero_kernel(float* __restrict__ p, int n)
{
  int i = blockIdx.x * 256 + threadIdx.x;
  if (i < n) p[i] = 0.f;
}

__global__ __launch_bounds__(128) void node_ln_kernel(
    float* __restrict__ Agg, bf16_t* __restrict__ hV)
{
  int bn = blockIdx.x;
  int c = threadIdx.x;
  size_t idx = (size_t)bn * H_ + c;
  float v = (float)hV[idx] + Agg[idx] * (1.0f / 30.0f);
  Agg[idx] = 0.f;               // re-arm accumulator for next layer
  __shared__ float red[4];
  float ss = wred(v), s2 = wred(v * v);
  int w = c >> 6, lane = c & 63;
  if (lane == 0) { red[w * 2] = ss; red[w * 2 + 1] = s2; }
  __syncthreads();
  float tot = red[0] + red[2], tot2 = red[1] + red[3];
  float mu = tot * (1.f / 128.f);
  float var = fmaxf(tot2 * (1.f / 128.f) - mu * mu, 0.f);
  float rstd = rsqrtf(var + 1e-5f);
  hV[idx] = (bf16_t)((v - mu) * rstd);
}

// ================= launch =================
extern "C" void kernel_launch(void* const* d_in, const int* in_sizes, int n_in,
                              void* d_out, int out_size, void* d_ws, size_t ws_size,
                              hipStream_t stream)
{
  const int* E_idx  = (const int*)d_in[2];
  const int* invmap = (const int*)d_in[3];

  char* ws = (char*)d_ws;
  size_t woff = 0;
  auto walloc = [&](size_t bytes) -> char* {
    char* p = ws + woff; woff += (bytes + 255) & ~(size_t)255; return p;
  };
  int*    flag  = (int*)walloc(4);
  bf16_t* WtOut = (bf16_t*)walloc((size_t)51200 * 2);
  bf16_t* outbc = (bf16_t*)walloc((size_t)400 * 2);
  bf16_t* hE    = (bf16_t*)walloc((size_t)RT * H_ * 2);

  char* ob = (char*)d_out;
  bf16_t* t0 = (bf16_t*)ob;
  bf16_t* t1 = (bf16_t*)(ob + (size_t)RT * H_ * 2);
  size_t ooff = (size_t)RT * H_ * 2 * 2;
  auto oalloc = [&](size_t bytes) -> char* {
    char* p = ob + ooff; ooff += (bytes + 255) & ~(size_t)255; return p;
  };
  bf16_t* WtV  = (bf16_t*)oalloc(16384 * 2);
  bf16_t* bvc  = (bf16_t*)oalloc(128 * 2);
  bf16_t* WtE  = (bf16_t*)oalloc(16384 * 2);
  bf16_t* bec  = (bf16_t*)oalloc(128 * 2);
  bf16_t* Wtn1 = (bf16_t*)oalloc((size_t)147456 * 2);
  bf16_t* nb1c = (bf16_t*)oalloc(384 * 2);
  bf16_t* Wtn2 = (bf16_t*)oalloc((size_t)49152 * 2);
  bf16_t* nb2c = (bf16_t*)oalloc(384 * 2);
  bf16_t* Wtn3 = (bf16_t*)oalloc((size_t)49152 * 2);
  bf16_t* nb3c = (bf16_t*)oalloc(384 * 2);
  bf16_t* Wtnd1 = (bf16_t*)oalloc((size_t)196608 * 2);
  bf16_t* nbd1c = (bf16_t*)oalloc(1536 * 2);
  bf16_t* Wtnd2 = (bf16_t*)oalloc((size_t)196608 * 2);
  bf16_t* nbd2c = (bf16_t*)oalloc(384 * 2);
  bf16_t* Wte1 = (bf16_t*)oalloc((size_t)147456 * 2);
  bf16_t* eb1c = (bf16_t*)oalloc(384 * 2);
  bf16_t* Wte2 = (bf16_t*)oalloc((size_t)49152 * 2);
  bf16_t* eb2c = (bf16_t*)oalloc(384 * 2);
  bf16_t* Wte3 = (bf16_t*)oalloc((size_t)49152 * 2);
  bf16_t* eb3c = (bf16_t*)oalloc(384 * 2);
  bf16_t* Wted1 = (bf16_t*)oalloc((size_t)196608 * 2);
  bf16_t* ebd1c = (bf16_t*)oalloc(1536 * 2);
  bf16_t* Wted2 = (bf16_t*)oalloc((size_t)196608 * 2);
  bf16_t* ebd2c = (bf16_t*)oalloc(384 * 2);
  float*  Ubuf = (float*)oalloc((size_t)BN_ * 128 * 4);
  float*  Gbuf = (float*)oalloc((size_t)BN_ * 128 * 4);
  bf16_t* hV   = (bf16_t*)oalloc((size_t)BN_ * 128 * 2);
  float*  ma   = (float*)oalloc((size_t)RT * 4);
  bf16_t* xm   = (bf16_t*)oalloc((size_t)BN_ * 2);
  float*  xmf  = (float*)oalloc((size_t)BN_ * 4);
  float*  Abuf = (float*)oalloc((size_t)BN_ * 128 * 4);   // node agg (1 MB)

  ConvArgs ca;
  struct D { int idx; void* dst; int K; int N; };
  const D dl[29] = {
    {0, t1, 0, 0}, {1, t0, 0, 0}, {4, xm, 0, 0},
    {5, WtV, 128, 128}, {6, bvc, 0, 0}, {7, WtE, 128, 128}, {8, bec, 0, 0},
    {9, Wtn1, 384, 128}, {10, nb1c, 0, 0}, {11, Wtn2, 128, 128}, {12, nb2c, 0, 0},
    {13, Wtn3, 128, 128}, {14, nb3c, 0, 0},
    {15, Wtnd1, 128, 512}, {16, nbd1c, 0, 0}, {17, Wtnd2, 512, 128}, {18, nbd2c, 0, 0},
    {19, Wte1, 384, 128}, {20, eb1c, 0, 0}, {21, Wte2, 128, 128}, {22, eb2c, 0, 0},
    {23, Wte3, 128, 128}, {24, eb3c, 0, 0},
    {25, Wted1, 128, 512}, {26, ebd1c, 0, 0}, {27, Wted2, 512, 128}, {28, ebd2c, 0, 0},
    {29, WtOut, 128, 400}, {30, outbc, 0, 0}
  };
  int total8 = 0;
  for (int i = 0; i < 29; ++i) {
    ca.s[i].src = d_in[dl[i].idx];
    ca.s[i].dst = dl[i].dst;
    ca.s[i].n   = in_sizes[dl[i].idx];
    ca.s[i].K   = dl[i].K;
    ca.s[i].N   = dl[i].N;
    total8 += ca.s[i].n >> 3;
  }

  auto g = [&](dim3 grid, const bf16_t* A, int lda, const bf16_t* Bt, int ldb,
               int koff, const bf16_t* bias, int N, int K, int epi,
               bf16_t* C, float* Cf, float* Cf1, int koff1,
               bf16_t* resid, const float* mvec, int row0g) {
    gk<<<grid, 256, 0, stream>>>(A, lda, Bt, ldb, koff, bias, N, K, epi,
        C, Cf, Cf1, koff1, Ubuf, Gbuf, E_idx, resid, mvec, row0g,
        invmap, flag, d_out);
  };
  const float* NOM = nullptr;

  flag_kernel<<<1, 64, 0, stream>>>((const uint32_t*)d_in[4], flag);
  conv_kernel<<<(total8 + 255) / 256, 256, 0, stream>>>(ca, 29, total8, flag);
  mask_kernel<<<RT / 256, 256, 0, stream>>>(xm, E_idx, ma, xmf);
  zero_kernel<<<(BN_ * 128) / 256, 256, 0, stream>>>(Abuf, BN_ * 128);

  // embeds
  g(dim3(1, BN_ / 128), t1, 128, WtV, 128, 0, bvc, 128, 128, EPI_PLAIN,
    hV, nullptr, nullptr, 0, nullptr, NOM, 0);
  g(dim3(1, RT / 128), t0, 128, WtE, 128, 0, bec, 128, 128, EPI_PLAIN,
    hE, nullptr, nullptr, 0, nullptr, NOM, 0);

  for (int l = 0; l < L_; ++l) {
    // ---- node update ----
    g(dim3(1, BN_ / 128, 2), hV, 128, Wtn1 + (size_t)l * 49152, 384, 0,
      nb1c + l * 128, 128, 128, EPI_F32,
      nullptr, Ubuf, Gbuf, 128, nullptr, NOM, 0);
    {
      GCArgs na{};
      na.Ain = hE;
      na.W1 = Wtn1 + (size_t)l * 49152; na.koff1 = 256; na.ldw1 = 384;
      na.W2 = Wtn2 + (size_t)l * 16384; na.b2 = nb2c + l * 128;
      na.W3 = Wtn3 + (size_t)l * 16384; na.b3 = nb3c + l * 128;
      na.U = Ubuf; na.G = Gbuf; na.E = E_idx;
      na.ma = ma; na.Agg = Abuf;
      gc<0><<<RT / 128, 256, 0, stream>>>(na);
    }
    node_ln_kernel<<<BN_, 128, 0, stream>>>(Abuf, hV);
    {
      GCArgs nf{};
      nf.Ain = hV;
      nf.Wd1 = Wtnd1 + (size_t)l * 65536; nf.bd1 = nbd1c + l * 512;
      nf.Wd2 = Wtnd2 + (size_t)l * 65536; nf.bd2 = nbd2c + l * 128;
      nf.mvec = xmf; nf.outF = hV;
      nf.Wug = Wte1 + (size_t)l * 49152; nf.bug = eb1c + l * 128;
      nf.Uo = Ubuf; nf.Go = Gbuf;
      gc<2><<<BN_ / 128, 256, 0, stream>>>(nf);
    }
    // ---- edge update (fully fused; U/G already emitted by gc<2>) ----
    {
      GCArgs ea{};
      ea.Ain = hE;
      ea.W1 = Wte1 + (size_t)l * 49152; ea.koff1 = 128; ea.ldw1 = 384;
      ea.W2 = Wte2 + (size_t)l * 16384; ea.b2 = eb2c + l * 128;
      ea.W3 = Wte3 + (size_t)l * 16384; ea.b3 = eb3c + l * 128;
      ea.U = Ubuf; ea.G = Gbuf; ea.E = E_idx;
      ea.Wd1 = Wted1 + (size_t)l * 65536; ea.bd1 = ebd1c + l * 512;
      ea.Wd2 = Wted2 + (size_t)l * 65536; ea.bd2 = ebd2c + l * 128;
      ea.mvec = ma; ea.outF = hE;
      gc<1><<<RT / 128, 256, 0, stream>>>(ea);
    }
  }

  // output head: fused merge_dups gather, dtype-aware store
  g(dim3(4, RT / 128), hE, 128, WtOut, 128, 0, outbc, ODIM_, 128, EPI_OUT,
    nullptr, nullptr, nullptr, 0, nullptr, NOM, 0);
}

// Round 5
// 723.522 us; speedup vs baseline: 1.3591x; 1.3591x over previous
//
#include <hip/hip_runtime.h>
#include <hip/hip_bf16.h>
#include <stdint.h>

// PairEnergies GNN on MI355X — round 11.
// Fix r10's occupancy collapse: gfx950 unified VGPR file means arch(216)+acc
// (128) > 256 -> 1 wave/SIMD under (256,1). Back to (256,2) [<=256 total] and
// make the FFN actually FIT: hidden processed in 8x64-col chunks (accH 64->32
// regs), weight staging via global_load_lds + __syncthreads (r8-proven; the
// r9/r10 reg-prefetch never helped and inflated liveness). Keeps r9 wins:
// LDS-resident S3 residual, node-agg via LDS atomics, U/G folded into gc<2>.

typedef __bf16 bf16_t;
typedef __attribute__((ext_vector_type(8))) __bf16 bf16x8;
typedef __attribute__((ext_vector_type(4))) float f32x4;

#define B_    2
#define N_    1024
#define KN    30
#define H_    128
#define L_    3
#define ODIM_ 400
#define NK    (N_ * KN)        // 30720
#define RT    (B_ * N_ * KN)   // 61440
#define BN_   (B_ * N_)        // 2048

#define EPI_PLAIN 0
#define EPI_RELU  1
#define EPI_F32   2
#define EPI_LN    4
#define EPI_OUT   5

__device__ __forceinline__ float wred(float v) {
#pragma unroll
  for (int off = 32; off > 0; off >>= 1) v += __shfl_xor(v, off, 64);
  return v;
}

// async global->LDS, 16B per lane; lds base must be wave-uniform.
__device__ __forceinline__ void gld16(const bf16_t* g, bf16_t* l) {
  __builtin_amdgcn_global_load_lds(
      (__attribute__((address_space(1))) void*)(g),
      (__attribute__((address_space(3))) void*)(l), 16, 0, 0);
}

// one BK=64 MFMA round; A 128 rows, B NI*16*2 cols half (NI=4: 128, NI=2: 64)
template<int NI>
__device__ __forceinline__ void mmN(const bf16_t* __restrict__ Ah,
                                    const bf16_t* __restrict__ Bh,
                                    int wm, int wn, int fm, int q, int fx,
                                    f32x4 (&acc)[4][NI])
{
#pragma unroll
  for (int h = 0; h < 2; ++h) {
    const int slot = ((((h << 2) | q) ^ fx) << 3);
    bf16x8 af[4], bfv[NI];
#pragma unroll
    for (int mi = 0; mi < 4; ++mi)
      af[mi] = *reinterpret_cast<const bf16x8*>(
          &Ah[(wm * 64 + mi * 16 + fm) * 64 + slot]);
#pragma unroll
    for (int ni = 0; ni < NI; ++ni)
      bfv[ni] = *reinterpret_cast<const bf16x8*>(
          &Bh[(wn * (NI * 16) + ni * 16 + fm) * 64 + slot]);
#pragma unroll
    for (int mi = 0; mi < 4; ++mi)
#pragma unroll
      for (int ni = 0; ni < NI; ++ni)
        acc[mi][ni] = __builtin_amdgcn_mfma_f32_16x16x32_bf16(
            af[mi], bfv[ni], acc[mi][ni], 0, 0, 0);
  }
}

// ================= fused chain kernel =================
struct GCArgs {
  const bf16_t* Ain;
  const bf16_t* W1; int koff1; int ldw1;
  const bf16_t* W2; const bf16_t* b2;
  const bf16_t* W3; const bf16_t* b3;
  const float* U; const float* G; const int* E;
  const float* ma;          // mask_attend (MODE0 scale)
  float* Agg;               // MODE0: atomic node accumulator [BN_*128]
  const bf16_t* Wd1; const bf16_t* bd1;
  const bf16_t* Wd2; const bf16_t* bd2;
  const float* mvec;        // final-LN row mask: ma (MODE1) / xmf (MODE2)
  bf16_t* outF;             // hE (MODE1) / hV (MODE2)
  const bf16_t* Wug; const bf16_t* bug;  // MODE2: W1e, eb1c for U/G emit
  float* Uo; float* Go;
};

template<int MODE>
__global__ __launch_bounds__(256, 2) void gc(GCArgs a)
{
  __shared__ __align__(16) bf16_t bufA[2][8192];   // 32 KB
  __shared__ __align__(16) bf16_t bufB[2][8192];   // 32 KB
  __shared__ __align__(16) bf16_t Ws[8192];        // 16 KB weights / LN / agg
  float* lnS  = (float*)Ws;
  float* lnS2 = lnS + 256;
  float* aggS = (float*)Ws;                        // MODE0: [6][128]

  const int tid = threadIdx.x;
  const int w = tid >> 6, l = tid & 63;
  const int wm = w & 1, wn = w >> 1;
  const int row0 = blockIdx.x * 128;
  const int lr = l >> 3;
  const int kg8 = ((l & 7) ^ lr) << 3;   // swizzled source granule (elems)
  const int fm = l & 15, q = l >> 4, fx = fm & 7;

  // stage a 128-row x 64-K weight tile into Ws (full)
  auto stage128 = [&](const bf16_t* W, int ldw, int koff) {
    const bf16_t* gb = W + (size_t)(w * 32 + lr) * ldw + koff + kg8;
#pragma unroll
    for (int s = 0; s < 4; ++s)
      gld16(gb + (size_t)(s * 8) * ldw, &Ws[w * 2048 + s * 512]);
  };
  // stage a 64-row x 64-K weight tile into Ws (first 8KB)
  auto stage64 = [&](const bf16_t* W, int ldw, int koff) {
    const bf16_t* gb = W + (size_t)(w * 16 + lr) * ldw + koff + kg8;
#pragma unroll
    for (int s = 0; s < 2; ++s)
      gld16(gb + (size_t)(s * 8) * ldw, &Ws[w * 1024 + s * 512]);
  };

  auto do_gemm = [&](const bf16_t* SRC, const bf16_t* W, int koff, int ldw,
                     f32x4 (&acc)[4][4]) {
#pragma unroll
    for (int kt = 0; kt < 2; ++kt) {
      __syncthreads();
      stage128(W, ldw, koff + kt * 64);
      __syncthreads();
      mmN<4>(SRC + kt * 8192, Ws, wm, wn, fm, q, fx, acc);
    }
  };

  auto wb = [&](f32x4 (&acc)[4][4], bf16_t* dst) {
#pragma unroll
    for (int mi = 0; mi < 4; ++mi)
#pragma unroll
      for (int rr = 0; rr < 4; ++rr) {
        int row = wm * 64 + mi * 16 + q * 4 + rr;
#pragma unroll
        for (int ni = 0; ni < 4; ++ni) {
          int cl = ni * 16 + fm;
          dst[wn * 8192 + row * 64 +
              ((((cl >> 3) ^ (row & 7)) << 3) | (cl & 7))] =
              (bf16_t)acc[mi][ni][rr];
        }
      }
  };

  // ---- stage activation tile ----
  {
    bf16_t* dst = (MODE == 2) ? bufB[0] : bufA[0];
    const bf16_t* gb = a.Ain + (size_t)(row0 + w * 32 + lr) * 128 + kg8;
#pragma unroll
    for (int kt = 0; kt < 2; ++kt)
#pragma unroll
      for (int s = 0; s < 4; ++s)
        gld16(gb + (size_t)(s * 8) * 128 + kt * 64,
              dst + kt * 8192 + w * 2048 + s * 512);
  }

  if constexpr (MODE <= 1) {
    // ---- S1: m1 = relu(A @ W1(koff) + U + G) -> bufB ----
    f32x4 acc1[4][4] = {};
    do_gemm(bufA[0], a.W1, a.koff1, a.ldw1, acc1);
#pragma unroll
    for (int mi = 0; mi < 4; ++mi)
#pragma unroll
      for (int rr = 0; rr < 4; ++rr) {
        int rg = row0 + wm * 64 + mi * 16 + q * 4 + rr;
        const float* Ur = a.U + (size_t)(rg / KN) * 128;
        const float* Gr = a.G + (size_t)((rg / NK) * N_ + a.E[rg]) * 128;
#pragma unroll
        for (int ni = 0; ni < 4; ++ni) {
          int col = wn * 64 + ni * 16 + fm;
          acc1[mi][ni][rr] = fmaxf(acc1[mi][ni][rr] + Ur[col] + Gr[col], 0.f);
        }
      }
    wb(acc1, bufB[0]);       // bufB untouched before; visibility via next sync

    // ---- S2: m2 = relu(m1 @ W2 + b2) ----
    f32x4 acc2[4][4] = {};
    do_gemm(bufB[0], a.W2, 0, 128, acc2);
#pragma unroll
    for (int mi = 0; mi < 4; ++mi)
#pragma unroll
      for (int rr = 0; rr < 4; ++rr)
#pragma unroll
        for (int ni = 0; ni < 4; ++ni) {
          int col = wn * 64 + ni * 16 + fm;
          acc2[mi][ni][rr] = fmaxf(acc2[mi][ni][rr] + (float)a.b2[col], 0.f);
        }
    __syncthreads();         // all waves done reading m1 from bufB
    wb(acc2, bufB[0]);

    // ---- S3: m3 = m2 @ W3 ----
    f32x4 acc3[4][4] = {};
    do_gemm(bufB[0], a.W3, 0, 128, acc3);

    if constexpr (MODE == 0) {
      // node aggregation: aggS[node_local][col] += (m3+b3)*ma, then global
      __syncthreads();                         // Ws free
      for (int i = tid; i < 768; i += 256) aggS[i] = 0.f;
      __syncthreads();
      const int nb0 = row0 / KN;
#pragma unroll
      for (int mi = 0; mi < 4; ++mi)
#pragma unroll
        for (int rr = 0; rr < 4; ++rr) {
          int rg = row0 + wm * 64 + mi * 16 + q * 4 + rr;
          float mav = a.ma[rg];
          int nl = rg / KN - nb0;
#pragma unroll
          for (int ni = 0; ni < 4; ++ni) {
            int col = wn * 64 + ni * 16 + fm;
            atomicAdd(&aggS[nl * 128 + col],
                      (acc3[mi][ni][rr] + (float)a.b3[col]) * mav);
          }
        }
      __syncthreads();
      const int nbL = (row0 + 127) / KN;
      for (int i = tid; i < 768; i += 256) {
        int ng = nb0 + (i >> 7);
        if (ng <= nbL)
          atomicAdd(&a.Agg[(size_t)ng * 128 + (i & 127)], aggS[i]);
      }
      return;
    } else {
      // S3-LN: X = LN(hE(bufA) + m3 + b3) -> bufB
      __syncthreads();       // Ws->lnS reuse safe; bufB m2 reads done
#pragma unroll
      for (int mi = 0; mi < 4; ++mi)
#pragma unroll
        for (int rr = 0; rr < 4; ++rr) {
          int lrow = wm * 64 + mi * 16 + q * 4 + rr;
          float s = 0.f, s2 = 0.f;
#pragma unroll
          for (int ni = 0; ni < 4; ++ni) {
            int cl = ni * 16 + fm;
            float rv = (float)bufA[wn][lrow * 64 +
                ((((cl >> 3) ^ (lrow & 7)) << 3) | (cl & 7))];
            float v = acc3[mi][ni][rr] + (float)a.b3[wn * 64 + cl] + rv;
            acc3[mi][ni][rr] = v;
            s += v; s2 += v * v;
          }
#pragma unroll
          for (int d = 1; d < 16; d <<= 1) {
            s += __shfl_xor(s, d, 64); s2 += __shfl_xor(s2, d, 64);
          }
          if (fm == (mi * 4 + rr)) { lnS[wn * 128 + lrow] = s;
                                     lnS2[wn * 128 + lrow] = s2; }
        }
      __syncthreads();
#pragma unroll
      for (int mi = 0; mi < 4; ++mi)
#pragma unroll
        for (int rr = 0; rr < 4; ++rr) {
          int lrow = wm * 64 + mi * 16 + q * 4 + rr;
          float st = lnS[lrow] + lnS[128 + lrow];
          float st2 = lnS2[lrow] + lnS2[128 + lrow];
          float mu = st * (1.f / 128.f);
          float var = fmaxf(st2 * (1.f / 128.f) - mu * mu, 0.f);
          float rstd = rsqrtf(var + 1e-5f);
#pragma unroll
          for (int ni = 0; ni < 4; ++ni) {
            int cl = ni * 16 + fm;
            bufB[wn][lrow * 64 +
                ((((cl >> 3) ^ (lrow & 7)) << 3) | (cl & 7))] =
                (bf16_t)((acc3[mi][ni][rr] - mu) * rstd);
          }
        }
    }
  }

  // ---- FFN: accF = sum_c relu(X @ Wd1_c + bd1_c) @ Wd2_c ; X in bufB ----
  // 8 chunks of 64 hidden cols: accH [4][2] (32 regs) + accF [4][4] (64).
  {
    f32x4 accF[4][4] = {};
#pragma unroll 1
    for (int c = 0; c < 8; ++c) {
      const bf16_t* W1c = a.Wd1 + (size_t)(c * 64) * 128;
      f32x4 accH[4][2] = {};
#pragma unroll
      for (int kt = 0; kt < 2; ++kt) {
        __syncthreads();
        stage64(W1c, 128, kt * 64);
        __syncthreads();
        mmN<2>(bufB[0] + kt * 8192, Ws, wm, wn, fm, q, fx, accH);
      }
      // bias + relu, write H chunk [128][64] -> bufA[0]
#pragma unroll
      for (int mi = 0; mi < 4; ++mi)
#pragma unroll
        for (int rr = 0; rr < 4; ++rr) {
          int row = wm * 64 + mi * 16 + q * 4 + rr;
#pragma unroll
          for (int ni = 0; ni < 2; ++ni) {
            int cH = wn * 32 + ni * 16 + fm;     // 0..63 within chunk
            float hv = fmaxf(accH[mi][ni][rr] +
                             (float)a.bd1[c * 64 + cH], 0.f);
            bufA[0][row * 64 +
                ((((cH >> 3) ^ (row & 7)) << 3) | (cH & 7))] = (bf16_t)hv;
          }
        }
      __syncthreads();       // H visible; Ws free
      stage128(a.Wd2, 512, c * 64);
      __syncthreads();
      mmN<4>(bufA[0], Ws, wm, wn, fm, q, fx, accF);
    }

    // final LN: out = LN(X + accF + bd2) * mvec
    __syncthreads();         // Ws -> lnS reuse safe
#pragma unroll
    for (int mi = 0; mi < 4; ++mi)
#pragma unroll
      for (int rr = 0; rr < 4; ++rr) {
        int lrow = wm * 64 + mi * 16 + q * 4 + rr;
        float s = 0.f, s2 = 0.f;
#pragma unroll
        for (int ni = 0; ni < 4; ++ni) {
          int cl = ni * 16 + fm;
          float xv = (float)bufB[wn][lrow * 64 +
              ((((cl >> 3) ^ (lrow & 7)) << 3) | (cl & 7))];
          float v = accF[mi][ni][rr] + (float)a.bd2[wn * 64 + cl] + xv;
          accF[mi][ni][rr] = v;
          s += v; s2 += v * v;
        }
#pragma unroll
        for (int d = 1; d < 16; d <<= 1) {
          s += __shfl_xor(s, d, 64); s2 += __shfl_xor(s2, d, 64);
        }
        if (fm == (mi * 4 + rr)) { lnS[wn * 128 + lrow] = s;
                                   lnS2[wn * 128 + lrow] = s2; }
      }
    __syncthreads();
#pragma unroll
    for (int mi = 0; mi < 4; ++mi)
#pragma unroll
      for (int rr = 0; rr < 4; ++rr) {
        int lrow = wm * 64 + mi * 16 + q * 4 + rr;
        size_t rg = (size_t)(row0 + lrow);
        float st = lnS[lrow] + lnS[128 + lrow];
        float st2 = lnS2[lrow] + lnS2[128 + lrow];
        float mu = st * (1.f / 128.f);
        float var = fmaxf(st2 * (1.f / 128.f) - mu * mu, 0.f);
        float rstd = rsqrtf(var + 1e-5f);
        float mk = a.mvec[rg];
#pragma unroll
        for (int ni = 0; ni < 4; ++ni) {
          int col = wn * 64 + ni * 16 + fm;
          float ov = (accF[mi][ni][rr] - mu) * rstd * mk;
          a.outF[rg * 128 + col] = (bf16_t)ov;
          if constexpr (MODE == 2) accF[mi][ni][rr] = ov;
        }
      }

    if constexpr (MODE == 2) {
      // emit edge-phase U/G from the fresh hV tile
      __syncthreads();       // all waves done reading X from bufB
      wb(accF, bufB[0]);     // hV_new -> bufB (swizzled)
      f32x4 accU[4][4] = {};
      do_gemm(bufB[0], a.Wug, 0, 384, accU);
#pragma unroll
      for (int mi = 0; mi < 4; ++mi)
#pragma unroll
        for (int rr = 0; rr < 4; ++rr) {
          size_t rg = (size_t)(row0 + wm * 64 + mi * 16 + q * 4 + rr);
#pragma unroll
          for (int ni = 0; ni < 4; ++ni) {
            int col = wn * 64 + ni * 16 + fm;
            a.Uo[rg * 128 + col] = accU[mi][ni][rr] + (float)a.bug[col];
          }
        }
      f32x4 accG[4][4] = {};
      do_gemm(bufB[0], a.Wug, 256, 384, accG);
#pragma unroll
      for (int mi = 0; mi < 4; ++mi)
#pragma unroll
        for (int rr = 0; rr < 4; ++rr) {
          size_t rg = (size_t)(row0 + wm * 64 + mi * 16 + q * 4 + rr);
#pragma unroll
          for (int ni = 0; ni < 4; ++ni) {
            int col = wn * 64 + ni * 16 + fm;
            a.Go[rg * 128 + col] = accG[mi][ni][rr];
          }
        }
    }
  }
}

// ================= unified 128x128 MFMA GEMM (embeds / node-UG / head) ====
__global__ __launch_bounds__(256) void gk(
    const bf16_t* __restrict__ A, int lda,
    const bf16_t* __restrict__ Bt, int ldb, int koff,
    const bf16_t* __restrict__ bias,
    int N, int K, int epi,
    bf16_t* __restrict__ C,
    float* __restrict__ Cf, float* __restrict__ Cf1, int koff1,
    const float* __restrict__ U, const float* __restrict__ G,
    const int* __restrict__ E_idx,
    bf16_t* __restrict__ resid, const float* __restrict__ mvec, int row0g,
    const int* __restrict__ inv, const int* __restrict__ flag,
    void* __restrict__ outp)
{
  __shared__ __align__(16) bf16_t As[128 * 64];
  __shared__ __align__(16) bf16_t Bs[128 * 64];
  __shared__ float lnS[2][128];
  __shared__ float lnS2[2][128];

  float* CfD = Cf;
  if (epi == EPI_F32 && blockIdx.z == 1) { koff = koff1; bias = nullptr; CfD = Cf1; }

  const int tid = threadIdx.x;
  const int w = tid >> 6, l = tid & 63;
  const int wm = w & 1, wn = w >> 1;
  const int row0 = blockIdx.y * 128;
  const int col0 = blockIdx.x * 128;
  const int lr = l >> 3;
  const int kg8 = ((l & 7) ^ lr) << 3;

  const bf16_t* ap[4];
  const bf16_t* bp[4];
#pragma unroll
  for (int s = 0; s < 4; ++s) {
    int rA = row0 + w * 32 + s * 8 + lr;
    const bf16_t* abase;
    if (epi == EPI_OUT) {
      int bb = rA / NK;
      abase = A + (size_t)(bb * NK + inv[rA]) * lda;
    } else {
      abase = A + (size_t)rA * lda;
    }
    ap[s] = abase + kg8;
    int rB = col0 + w * 32 + s * 8 + lr;
    if (rB >= N) rB = N - 1;
    bp[s] = Bt + (size_t)rB * ldb + koff + kg8;
  }

  const int fm = l & 15, q = l >> 4, fx = fm & 7;
  f32x4 acc[4][4] = {};

  for (int kt = 0; kt < K; kt += 64) {
    __syncthreads();
#pragma unroll
    for (int s = 0; s < 4; ++s)
      gld16(ap[s] + kt, &As[w * 2048 + s * 512]);
#pragma unroll
    for (int s = 0; s < 4; ++s)
      gld16(bp[s] + kt, &Bs[w * 2048 + s * 512]);
    __syncthreads();
#pragma unroll
    for (int h = 0; h < 2; ++h) {
      bf16x8 af[4], bfv[4];
#pragma unroll
      for (int mi = 0; mi < 4; ++mi)
        af[mi] = *reinterpret_cast<const bf16x8*>(
            &As[(wm * 64 + mi * 16 + fm) * 64 + ((((h << 2) | q) ^ fx) << 3)]);
#pragma unroll
      for (int ni = 0; ni < 4; ++ni)
        bfv[ni] = *reinterpret_cast<const bf16x8*>(
            &Bs[(wn * 64 + ni * 16 + fm) * 64 + ((((h << 2) | q) ^ fx) << 3)]);
#pragma unroll
      for (int mi = 0; mi < 4; ++mi)
#pragma unroll
        for (int ni = 0; ni < 4; ++ni)
          acc[mi][ni] = __builtin_amdgcn_mfma_f32_16x16x32_bf16(
              af[mi], bfv[ni], acc[mi][ni], 0, 0, 0);
    }
  }

  if (epi <= EPI_F32) {
#pragma unroll
    for (int ni = 0; ni < 4; ++ni) {
      int col = col0 + wn * 64 + ni * 16 + fm;
      if (col >= N) continue;
      float bv = bias ? (float)bias[col] : 0.f;
#pragma unroll
      for (int mi = 0; mi < 4; ++mi)
#pragma unroll
        for (int rr = 0; rr < 4; ++rr) {
          size_t rg = (size_t)(row0g + row0 + wm * 64 + mi * 16 + q * 4 + rr);
          float v = acc[mi][ni][rr] + bv;
          if (epi == EPI_RELU) v = fmaxf(v, 0.f);
          if (epi == EPI_F32) CfD[rg * N + col] = v;
          else                C[rg * N + col] = (bf16_t)v;
        }
    }
  } else if (epi == EPI_LN) {
#pragma unroll
    for (int mi = 0; mi < 4; ++mi)
#pragma unroll
      for (int rr = 0; rr < 4; ++rr) {
        int lrow = wm * 64 + mi * 16 + q * 4 + rr;
        size_t rg = (size_t)(row0g + row0 + lrow);
        float s = 0.f, s2 = 0.f;
#pragma unroll
        for (int ni = 0; ni < 4; ++ni) {
          int col = wn * 64 + ni * 16 + fm;
          float v = acc[mi][ni][rr] + (bias ? (float)bias[col] : 0.f)
                    + (float)resid[rg * 128 + col];
          acc[mi][ni][rr] = v;
          s += v; s2 += v * v;
        }
#pragma unroll
        for (int d = 1; d < 16; d <<= 1) {
          s += __shfl_xor(s, d, 64); s2 += __shfl_xor(s2, d, 64);
        }
        if (fm == (mi * 4 + rr)) { lnS[wn][lrow] = s; lnS2[wn][lrow] = s2; }
      }
    __syncthreads();
#pragma unroll
    for (int mi = 0; mi < 4; ++mi)
#pragma unroll
      for (int rr = 0; rr < 4; ++rr) {
        int lrow = wm * 64 + mi * 16 + q * 4 + rr;
        size_t rg = (size_t)(row0g + row0 + lrow);
        float st = lnS[0][lrow] + lnS[1][lrow];
        float st2 = lnS2[0][lrow] + lnS2[1][lrow];
        float mu = st * (1.f / 128.f);
        float var = fmaxf(st2 * (1.f / 128.f) - mu * mu, 0.f);
        float rstd = rsqrtf(var + 1e-5f);
        float mk = mvec ? mvec[rg] : 1.f;
#pragma unroll
        for (int ni = 0; ni < 4; ++ni) {
          int col = wn * 64 + ni * 16 + fm;
          resid[rg * 128 + col] = (bf16_t)((acc[mi][ni][rr] - mu) * rstd * mk);
        }
      }
  } else if (epi == EPI_OUT) {
    const int fl = *flag;
#pragma unroll
    for (int ni = 0; ni < 4; ++ni) {
      int col = col0 + wn * 64 + ni * 16 + fm;
      if (col >= ODIM_) continue;
      float bv = bias ? (float)bias[col] : 0.f;
#pragma unroll
      for (int mi = 0; mi < 4; ++mi)
#pragma unroll
        for (int rr = 0; rr < 4; ++rr) {
          size_t rg = (size_t)(row0 + wm * 64 + mi * 16 + q * 4 + rr);
          float v = acc[mi][ni][rr] + bv;
          size_t idx = rg * ODIM_ + col;
          if (fl) ((bf16_t*)outp)[idx] = (bf16_t)v;
          else    ((float*)outp)[idx]  = v;
        }
    }
  }
}

// ================= dtype sniff =================
__global__ void flag_kernel(const uint32_t* __restrict__ xm_raw,
                            int* __restrict__ flag)
{
  if (threadIdx.x == 0 && blockIdx.x == 0)
    *flag = (xm_raw[0] == 0x3F803F80u) ? 1 : 0;
}

// ================= fused convert (+ weight transpose) =================
struct ConvSeg { const void* src; void* dst; int n; int K; int N; };
struct ConvArgs { ConvSeg s[29]; };

__global__ __launch_bounds__(256) void conv_kernel(
    ConvArgs a, int nseg, int total8, const int* __restrict__ flag)
{
  int t = blockIdx.x * 256 + threadIdx.x;
  if (t >= total8) return;
  const int fl = *flag;
  int seg = 0, t8 = t;
  while (seg < nseg - 1 && t8 >= (a.s[seg].n >> 3)) { t8 -= a.s[seg].n >> 3; ++seg; }
  const ConvSeg sg = a.s[seg];
  const int e = t8 << 3;
  float vals[8];
  if (fl) {
    union { uint4 v; bf16_t b[8]; } u;
    u.v = *((const uint4*)sg.src + t8);
#pragma unroll
    for (int j = 0; j < 8; ++j) vals[j] = (float)u.b[j];
  } else {
    const float* sp = (const float*)sg.src + e;
#pragma unroll
    for (int j = 0; j < 8; ++j) vals[j] = sp[j];
  }
  if (sg.N == 0) {
    union { uint4 v; bf16_t b[8]; } o;
#pragma unroll
    for (int j = 0; j < 8; ++j) o.b[j] = (bf16_t)vals[j];
    *((uint4*)sg.dst + t8) = o.v;
  } else {
    const int KN_ = sg.K * sg.N;
    const int lay = e / KN_;
    const int rem = e - lay * KN_;
    const int k = rem / sg.N;
    const int n0 = rem - k * sg.N;
    bf16_t* dp = (bf16_t*)sg.dst + (size_t)lay * KN_ + k;
#pragma unroll
    for (int j = 0; j < 8; ++j)
      dp[(size_t)(n0 + j) * sg.K] = (bf16_t)vals[j];
  }
}

// ================= mask_attend (+ float x_mask side copy) =================
__global__ __launch_bounds__(256) void mask_kernel(
    const bf16_t* __restrict__ xm, const int* __restrict__ E_idx,
    float* __restrict__ ma, float* __restrict__ xmf)
{
  int r = blockIdx.x * 256 + threadIdx.x;
  if (r >= RT) return;
  if (r < BN_) xmf[r] = (float)xm[r];
  int b = r / NK;
  int n = (r / KN) % N_;
  ma[r] = (float)xm[b * N_ + E_idx[r]] * (float)xm[b * N_ + n];
}

// ================= zero + node LN =================
__global__ __launch_bounds__(256) void zero_kernel(float* __restrict__ p, int n)
{
  int i = blockIdx.x * 256 + threadIdx.x;
  if (i < n) p[i] = 0.f;
}

__global__ __launch_bounds__(128) void node_ln_kernel(
    float* __restrict__ Agg, bf16_t* __restrict__ hV)
{
  int bn = blockIdx.x;
  int c = threadIdx.x;
  size_t idx = (size_t)bn * H_ + c;
  float v = (float)hV[idx] + Agg[idx] * (1.0f / 30.0f);
  Agg[idx] = 0.f;               // re-arm accumulator for next layer
  __shared__ float red[4];
  float ss = wred(v), s2 = wred(v * v);
  int w = c >> 6, lane = c & 63;
  if (lane == 0) { red[w * 2] = ss; red[w * 2 + 1] = s2; }
  __syncthreads();
  float tot = red[0] + red[2], tot2 = red[1] + red[3];
  float mu = tot * (1.f / 128.f);
  float var = fmaxf(tot2 * (1.f / 128.f) - mu * mu, 0.f);
  float rstd = rsqrtf(var + 1e-5f);
  hV[idx] = (bf16_t)((v - mu) * rstd);
}

// ================= launch =================
extern "C" void kernel_launch(void* const* d_in, const int* in_sizes, int n_in,
                              void* d_out, int out_size, void* d_ws, size_t ws_size,
                              hipStream_t stream)
{
  const int* E_idx  = (const int*)d_in[2];
  const int* invmap = (const int*)d_in[3];

  char* ws = (char*)d_ws;
  size_t woff = 0;
  auto walloc = [&](size_t bytes) -> char* {
    char* p = ws + woff; woff += (bytes + 255) & ~(size_t)255; return p;
  };
  int*    flag  = (int*)walloc(4);
  bf16_t* WtOut = (bf16_t*)walloc((size_t)51200 * 2);
  bf16_t* outbc = (bf16_t*)walloc((size_t)400 * 2);
  bf16_t* hE    = (bf16_t*)walloc((size_t)RT * H_ * 2);

  char* ob = (char*)d_out;
  bf16_t* t0 = (bf16_t*)ob;
  bf16_t* t1 = (bf16_t*)(ob + (size_t)RT * H_ * 2);
  size_t ooff = (size_t)RT * H_ * 2 * 2;
  auto oalloc = [&](size_t bytes) -> char* {
    char* p = ob + ooff; ooff += (bytes + 255) & ~(size_t)255; return p;
  };
  bf16_t* WtV  = (bf16_t*)oalloc(16384 * 2);
  bf16_t* bvc  = (bf16_t*)oalloc(128 * 2);
  bf16_t* WtE  = (bf16_t*)oalloc(16384 * 2);
  bf16_t* bec  = (bf16_t*)oalloc(128 * 2);
  bf16_t* Wtn1 = (bf16_t*)oalloc((size_t)147456 * 2);
  bf16_t* nb1c = (bf16_t*)oalloc(384 * 2);
  bf16_t* Wtn2 = (bf16_t*)oalloc((size_t)49152 * 2);
  bf16_t* nb2c = (bf16_t*)oalloc(384 * 2);
  bf16_t* Wtn3 = (bf16_t*)oalloc((size_t)49152 * 2);
  bf16_t* nb3c = (bf16_t*)oalloc(384 * 2);
  bf16_t* Wtnd1 = (bf16_t*)oalloc((size_t)196608 * 2);
  bf16_t* nbd1c = (bf16_t*)oalloc(1536 * 2);
  bf16_t* Wtnd2 = (bf16_t*)oalloc((size_t)196608 * 2);
  bf16_t* nbd2c = (bf16_t*)oalloc(384 * 2);
  bf16_t* Wte1 = (bf16_t*)oalloc((size_t)147456 * 2);
  bf16_t* eb1c = (bf16_t*)oalloc(384 * 2);
  bf16_t* Wte2 = (bf16_t*)oalloc((size_t)49152 * 2);
  bf16_t* eb2c = (bf16_t*)oalloc(384 * 2);
  bf16_t* Wte3 = (bf16_t*)oalloc((size_t)49152 * 2);
  bf16_t* eb3c = (bf16_t*)oalloc(384 * 2);
  bf16_t* Wted1 = (bf16_t*)oalloc((size_t)196608 * 2);
  bf16_t* ebd1c = (bf16_t*)oalloc(1536 * 2);
  bf16_t* Wted2 = (bf16_t*)oalloc((size_t)196608 * 2);
  bf16_t* ebd2c = (bf16_t*)oalloc(384 * 2);
  float*  Ubuf = (float*)oalloc((size_t)BN_ * 128 * 4);
  float*  Gbuf = (float*)oalloc((size_t)BN_ * 128 * 4);
  bf16_t* hV   = (bf16_t*)oalloc((size_t)BN_ * 128 * 2);
  float*  ma   = (float*)oalloc((size_t)RT * 4);
  bf16_t* xm   = (bf16_t*)oalloc((size_t)BN_ * 2);
  float*  xmf  = (float*)oalloc((size_t)BN_ * 4);
  float*  Abuf = (float*)oalloc((size_t)BN_ * 128 * 4);   // node agg (1 MB)

  ConvArgs ca;
  struct D { int idx; void* dst; int K; int N; };
  const D dl[29] = {
    {0, t1, 0, 0}, {1, t0, 0, 0}, {4, xm, 0, 0},
    {5, WtV, 128, 128}, {6, bvc, 0, 0}, {7, WtE, 128, 128}, {8, bec, 0, 0},
    {9, Wtn1, 384, 128}, {10, nb1c, 0, 0}, {11, Wtn2, 128, 128}, {12, nb2c, 0, 0},
    {13, Wtn3, 128, 128}, {14, nb3c, 0, 0},
    {15, Wtnd1, 128, 512}, {16, nbd1c, 0, 0}, {17, Wtnd2, 512, 128}, {18, nbd2c, 0, 0},
    {19, Wte1, 384, 128}, {20, eb1c, 0, 0}, {21, Wte2, 128, 128}, {22, eb2c, 0, 0},
    {23, Wte3, 128, 128}, {24, eb3c, 0, 0},
    {25, Wted1, 128, 512}, {26, ebd1c, 0, 0}, {27, Wted2, 512, 128}, {28, ebd2c, 0, 0},
    {29, WtOut, 128, 400}, {30, outbc, 0, 0}
  };
  int total8 = 0;
  for (int i = 0; i < 29; ++i) {
    ca.s[i].src = d_in[dl[i].idx];
    ca.s[i].dst = dl[i].dst;
    ca.s[i].n   = in_sizes[dl[i].idx];
    ca.s[i].K   = dl[i].K;
    ca.s[i].N   = dl[i].N;
    total8 += ca.s[i].n >> 3;
  }

  auto g = [&](dim3 grid, const bf16_t* A, int lda, const bf16_t* Bt, int ldb,
               int koff, const bf16_t* bias, int N, int K, int epi,
               bf16_t* C, float* Cf, float* Cf1, int koff1,
               bf16_t* resid, const float* mvec, int row0g) {
    gk<<<grid, 256, 0, stream>>>(A, lda, Bt, ldb, koff, bias, N, K, epi,
        C, Cf, Cf1, koff1, Ubuf, Gbuf, E_idx, resid, mvec, row0g,
        invmap, flag, d_out);
  };
  const float* NOM = nullptr;

  flag_kernel<<<1, 64, 0, stream>>>((const uint32_t*)d_in[4], flag);
  conv_kernel<<<(total8 + 255) / 256, 256, 0, stream>>>(ca, 29, total8, flag);
  mask_kernel<<<RT / 256, 256, 0, stream>>>(xm, E_idx, ma, xmf);
  zero_kernel<<<(BN_ * 128) / 256, 256, 0, stream>>>(Abuf, BN_ * 128);

  // embeds
  g(dim3(1, BN_ / 128), t1, 128, WtV, 128, 0, bvc, 128, 128, EPI_PLAIN,
    hV, nullptr, nullptr, 0, nullptr, NOM, 0);
  g(dim3(1, RT / 128), t0, 128, WtE, 128, 0, bec, 128, 128, EPI_PLAIN,
    hE, nullptr, nullptr, 0, nullptr, NOM, 0);

  for (int l = 0; l < L_; ++l) {
    // ---- node U/G from hV ----
    g(dim3(1, BN_ / 128, 2), hV, 128, Wtn1 + (size_t)l * 49152, 384, 0,
      nb1c + l * 128, 128, 128, EPI_F32,
      nullptr, Ubuf, Gbuf, 128, nullptr, NOM, 0);
    // ---- node message + aggregation ----
    {
      GCArgs na{};
      na.Ain = hE;
      na.W1 = Wtn1 + (size_t)l * 49152; na.koff1 = 256; na.ldw1 = 384;
      na.W2 = Wtn2 + (size_t)l * 16384; na.b2 = nb2c + l * 128;
      na.W3 = Wtn3 + (size_t)l * 16384; na.b3 = nb3c + l * 128;
      na.U = Ubuf; na.G = Gbuf; na.E = E_idx;
      na.ma = ma; na.Agg = Abuf;
      gc<0><<<RT / 128, 256, 0, stream>>>(na);
    }
    node_ln_kernel<<<BN_, 128, 0, stream>>>(Abuf, hV);
    // ---- node FFN + edge U/G emit ----
    {
      GCArgs nf{};
      nf.Ain = hV;
      nf.Wd1 = Wtnd1 + (size_t)l * 65536; nf.bd1 = nbd1c + l * 512;
      nf.Wd2 = Wtnd2 + (size_t)l * 65536; nf.bd2 = nbd2c + l * 128;
      nf.mvec = xmf; nf.outF = hV;
      nf.Wug = Wte1 + (size_t)l * 49152; nf.bug = eb1c + l * 128;
      nf.Uo = Ubuf; nf.Go = Gbuf;
      gc<2><<<BN_ / 128, 256, 0, stream>>>(nf);
    }
    // ---- edge update (fully fused) ----
    {
      GCArgs ea{};
      ea.Ain = hE;
      ea.W1 = Wte1 + (size_t)l * 49152; ea.koff1 = 128; ea.ldw1 = 384;
      ea.W2 = Wte2 + (size_t)l * 16384; ea.b2 = eb2c + l * 128;
      ea.W3 = Wte3 + (size_t)l * 16384; ea.b3 = eb3c + l * 128;
      ea.U = Ubuf; ea.G = Gbuf; ea.E = E_idx;
      ea.Wd1 = Wted1 + (size_t)l * 65536; ea.bd1 = ebd1c + l * 512;
      ea.Wd2 = Wted2 + (size_t)l * 65536; ea.bd2 = ebd2c + l * 128;
      ea.mvec = ma; ea.outF = hE;
      gc<1><<<RT / 128, 256, 0, stream>>>(ea);
    }
  }

  // output head: fused merge_dups gather, dtype-aware store
  g(dim3(4, RT / 128), hE, 128, WtOut, 128, 0, outbc, ODIM_, 128, EPI_OUT,
    nullptr, nullptr, nullptr, 0, nullptr, NOM, 0);
}

// Round 6
// 701.081 us; speedup vs baseline: 1.4026x; 1.0320x over previous
//
#include <hip/hip_runtime.h>
#include <hip/hip_bf16.h>
#include <stdint.h>

// PairEnergies GNN on MI355X — round 12.
// r11 + (1) single reused accumulator accA[4][4] across all chain stages
// (explicit lifetime union -> AGPR demand 96, arch side gets ~160 under the
// (256,2) cap -> spill eliminated; r11 still wrote 27.4MB vs 15.7 legit);
// (2) FFN weight double-buffer: Wd1 chunk in Ws, Wd2 chunk in bufA[1] (free
// during FFN), issued one phase ahead with counted s_waitcnt vmcnt(4) (never
// drained mid-loop) + raw barriers + setprio around MFMA clusters.

typedef __bf16 bf16_t;
typedef __attribute__((ext_vector_type(8))) __bf16 bf16x8;
typedef __attribute__((ext_vector_type(4))) float f32x4;

#define B_    2
#define N_    1024
#define KN    30
#define H_    128
#define L_    3
#define ODIM_ 400
#define NK    (N_ * KN)        // 30720
#define RT    (B_ * N_ * KN)   // 61440
#define BN_   (B_ * N_)        // 2048

#define EPI_PLAIN 0
#define EPI_RELU  1
#define EPI_F32   2
#define EPI_LN    4
#define EPI_OUT   5

__device__ __forceinline__ float wred(float v) {
#pragma unroll
  for (int off = 32; off > 0; off >>= 1) v += __shfl_xor(v, off, 64);
  return v;
}

// async global->LDS, 16B per lane; lds base must be wave-uniform.
__device__ __forceinline__ void gld16(const bf16_t* g, bf16_t* l) {
  __builtin_amdgcn_global_load_lds(
      (__attribute__((address_space(1))) void*)(g),
      (__attribute__((address_space(3))) void*)(l), 16, 0, 0);
}

// LDS-op drain + barrier (publish ds_writes), no vmcnt drain.
__device__ __forceinline__ void barL() {
  asm volatile("s_waitcnt lgkmcnt(0)" ::: "memory");
  __builtin_amdgcn_s_barrier();
  __builtin_amdgcn_sched_barrier(0);
}
// counted-vmcnt barriers for the FFN pipeline
__device__ __forceinline__ void wait_v4_bar() {
  asm volatile("s_waitcnt vmcnt(4) lgkmcnt(0)" ::: "memory");
  __builtin_amdgcn_s_barrier();
  __builtin_amdgcn_sched_barrier(0);
}
__device__ __forceinline__ void wait_v0_bar() {
  asm volatile("s_waitcnt vmcnt(0) lgkmcnt(0)" ::: "memory");
  __builtin_amdgcn_s_barrier();
  __builtin_amdgcn_sched_barrier(0);
}

// one BK=64 MFMA round; A 128 rows, B NI*16*2 cols half (NI=4: 128, NI=2: 64)
template<int NI>
__device__ __forceinline__ void mmN(const bf16_t* __restrict__ Ah,
                                    const bf16_t* __restrict__ Bh,
                                    int wm, int wn, int fm, int q, int fx,
                                    f32x4 (&acc)[4][NI])
{
#pragma unroll
  for (int h = 0; h < 2; ++h) {
    const int slot = ((((h << 2) | q) ^ fx) << 3);
    bf16x8 af[4], bfv[NI];
#pragma unroll
    for (int mi = 0; mi < 4; ++mi)
      af[mi] = *reinterpret_cast<const bf16x8*>(
          &Ah[(wm * 64 + mi * 16 + fm) * 64 + slot]);
#pragma unroll
    for (int ni = 0; ni < NI; ++ni)
      bfv[ni] = *reinterpret_cast<const bf16x8*>(
          &Bh[(wn * (NI * 16) + ni * 16 + fm) * 64 + slot]);
#pragma unroll
    for (int mi = 0; mi < 4; ++mi)
#pragma unroll
      for (int ni = 0; ni < NI; ++ni)
        acc[mi][ni] = __builtin_amdgcn_mfma_f32_16x16x32_bf16(
            af[mi], bfv[ni], acc[mi][ni], 0, 0, 0);
  }
}

// ================= fused chain kernel =================
struct GCArgs {
  const bf16_t* Ain;
  const bf16_t* W1; int koff1; int ldw1;
  const bf16_t* W2; const bf16_t* b2;
  const bf16_t* W3; const bf16_t* b3;
  const float* U; const float* G; const int* E;
  const float* ma;          // mask_attend (MODE0 scale)
  float* Agg;               // MODE0: atomic node accumulator [BN_*128]
  const bf16_t* Wd1; const bf16_t* bd1;
  const bf16_t* Wd2; const bf16_t* bd2;
  const float* mvec;        // final-LN row mask: ma (MODE1) / xmf (MODE2)
  bf16_t* outF;             // hE (MODE1) / hV (MODE2)
  const bf16_t* Wug; const bf16_t* bug;  // MODE2: W1e, eb1c for U/G emit
  float* Uo; float* Go;
};

template<int MODE>
__global__ __launch_bounds__(256, 2) void gc(GCArgs a)
{
  __shared__ __align__(16) bf16_t bufA[2][8192];   // 32 KB
  __shared__ __align__(16) bf16_t bufB[2][8192];   // 32 KB
  __shared__ __align__(16) bf16_t Ws[8192];        // 16 KB weights / LN / agg
  float* lnS  = (float*)Ws;
  float* lnS2 = lnS + 256;
  float* aggS = (float*)Ws;                        // MODE0: [6][128]

  const int tid = threadIdx.x;
  const int w = tid >> 6, l = tid & 63;
  const int wm = w & 1, wn = w >> 1;
  const int row0 = blockIdx.x * 128;
  const int lr = l >> 3;
  const int kg8 = ((l & 7) ^ lr) << 3;   // swizzled source granule (elems)
  const int fm = l & 15, q = l >> 4, fx = fm & 7;

  // stage a 128-row x 64-K weight tile into Ws (full 16 KB)
  auto stage128 = [&](const bf16_t* W, int ldw, int koff) {
    const bf16_t* gb = W + (size_t)(w * 32 + lr) * ldw + koff + kg8;
#pragma unroll
    for (int s = 0; s < 4; ++s)
      gld16(gb + (size_t)(s * 8) * ldw, &Ws[w * 2048 + s * 512]);
  };
  // FFN: Wd1 chunk c (64 rows x 128 K): kt0 -> Ws[0..4096), kt1 -> Ws[4096..)
  auto stageWd1 = [&](int c) {
    const bf16_t* gb = a.Wd1 + (size_t)(c * 64 + w * 16 + lr) * 128 + kg8;
#pragma unroll
    for (int s = 0; s < 2; ++s) {
      gld16(gb + (size_t)(s * 8) * 128,      &Ws[w * 1024 + s * 512]);
      gld16(gb + (size_t)(s * 8) * 128 + 64, &Ws[4096 + w * 1024 + s * 512]);
    }
  };
  // FFN: Wd2 k-window c (128 rows x 64 K) -> bufA[1]
  auto stageWd2 = [&](int c) {
    const bf16_t* gb = a.Wd2 + (size_t)(w * 32 + lr) * 512 + c * 64 + kg8;
#pragma unroll
    for (int s = 0; s < 4; ++s)
      gld16(gb + (size_t)(s * 8) * 512, &bufA[1][w * 2048 + s * 512]);
  };

  auto do_gemm = [&](const bf16_t* SRC, const bf16_t* W, int koff, int ldw,
                     f32x4 (&acc)[4][4]) {
#pragma unroll
    for (int kt = 0; kt < 2; ++kt) {
      __syncthreads();
      stage128(W, ldw, koff + kt * 64);
      __syncthreads();
      mmN<4>(SRC + kt * 8192, Ws, wm, wn, fm, q, fx, acc);
    }
  };

  auto wb = [&](f32x4 (&acc)[4][4], bf16_t* dst) {
#pragma unroll
    for (int mi = 0; mi < 4; ++mi)
#pragma unroll
      for (int rr = 0; rr < 4; ++rr) {
        int row = wm * 64 + mi * 16 + q * 4 + rr;
#pragma unroll
        for (int ni = 0; ni < 4; ++ni) {
          int cl = ni * 16 + fm;
          dst[wn * 8192 + row * 64 +
              ((((cl >> 3) ^ (row & 7)) << 3) | (cl & 7))] =
              (bf16_t)acc[mi][ni][rr];
        }
      }
  };

  // single reused accumulator (keeps AGPR footprint at 64+32)
  f32x4 accA[4][4];
  auto zeroA = [&]() {
#pragma unroll
    for (int mi = 0; mi < 4; ++mi)
#pragma unroll
      for (int ni = 0; ni < 4; ++ni)
        accA[mi][ni] = f32x4{0.f, 0.f, 0.f, 0.f};
  };

  // ---- stage activation tile ----
  {
    bf16_t* dst = (MODE == 2) ? bufB[0] : bufA[0];
    const bf16_t* gb = a.Ain + (size_t)(row0 + w * 32 + lr) * 128 + kg8;
#pragma unroll
    for (int kt = 0; kt < 2; ++kt)
#pragma unroll
      for (int s = 0; s < 4; ++s)
        gld16(gb + (size_t)(s * 8) * 128 + kt * 64,
              dst + kt * 8192 + w * 2048 + s * 512);
  }
  if constexpr (MODE == 2) stageWd1(0);   // FFN c0 weights in flight

  if constexpr (MODE <= 1) {
    // ---- S1: m1 = relu(A @ W1(koff) + U + G) -> bufB ----
    zeroA();
    do_gemm(bufA[0], a.W1, a.koff1, a.ldw1, accA);
#pragma unroll
    for (int mi = 0; mi < 4; ++mi)
#pragma unroll
      for (int rr = 0; rr < 4; ++rr) {
        int rg = row0 + wm * 64 + mi * 16 + q * 4 + rr;
        const float* Ur = a.U + (size_t)(rg / KN) * 128;
        const float* Gr = a.G + (size_t)((rg / NK) * N_ + a.E[rg]) * 128;
#pragma unroll
        for (int ni = 0; ni < 4; ++ni) {
          int col = wn * 64 + ni * 16 + fm;
          accA[mi][ni][rr] = fmaxf(accA[mi][ni][rr] + Ur[col] + Gr[col], 0.f);
        }
      }
    wb(accA, bufB[0]);

    // ---- S2: m2 = relu(m1 @ W2 + b2) ----
    zeroA();
    do_gemm(bufB[0], a.W2, 0, 128, accA);
#pragma unroll
    for (int mi = 0; mi < 4; ++mi)
#pragma unroll
      for (int rr = 0; rr < 4; ++rr)
#pragma unroll
        for (int ni = 0; ni < 4; ++ni) {
          int col = wn * 64 + ni * 16 + fm;
          accA[mi][ni][rr] = fmaxf(accA[mi][ni][rr] + (float)a.b2[col], 0.f);
        }
    __syncthreads();         // all waves done reading m1 from bufB
    wb(accA, bufB[0]);

    // ---- S3: m3 = m2 @ W3 ----
    zeroA();
    do_gemm(bufB[0], a.W3, 0, 128, accA);

    if constexpr (MODE == 0) {
      // node aggregation: aggS[node_local][col] += (m3+b3)*ma, then global
      __syncthreads();                         // Ws free
      for (int i = tid; i < 768; i += 256) aggS[i] = 0.f;
      __syncthreads();
      const int nb0 = row0 / KN;
#pragma unroll
      for (int mi = 0; mi < 4; ++mi)
#pragma unroll
        for (int rr = 0; rr < 4; ++rr) {
          int rg = row0 + wm * 64 + mi * 16 + q * 4 + rr;
          float mav = a.ma[rg];
          int nl = rg / KN - nb0;
#pragma unroll
          for (int ni = 0; ni < 4; ++ni) {
            int col = wn * 64 + ni * 16 + fm;
            atomicAdd(&aggS[nl * 128 + col],
                      (accA[mi][ni][rr] + (float)a.b3[col]) * mav);
          }
        }
      __syncthreads();
      const int nbL = (row0 + 127) / KN;
      for (int i = tid; i < 768; i += 256) {
        int ng = nb0 + (i >> 7);
        if (ng <= nbL)
          atomicAdd(&a.Agg[(size_t)ng * 128 + (i & 127)], aggS[i]);
      }
      return;
    } else {
      // S3-LN: X = LN(hE(bufA) + m3 + b3) -> bufB
      __syncthreads();       // Ws->lnS reuse safe; bufB m2 reads done
#pragma unroll
      for (int mi = 0; mi < 4; ++mi)
#pragma unroll
        for (int rr = 0; rr < 4; ++rr) {
          int lrow = wm * 64 + mi * 16 + q * 4 + rr;
          float s = 0.f, s2 = 0.f;
#pragma unroll
          for (int ni = 0; ni < 4; ++ni) {
            int cl = ni * 16 + fm;
            float rv = (float)bufA[wn][lrow * 64 +
                ((((cl >> 3) ^ (lrow & 7)) << 3) | (cl & 7))];
            float v = accA[mi][ni][rr] + (float)a.b3[wn * 64 + cl] + rv;
            accA[mi][ni][rr] = v;
            s += v; s2 += v * v;
          }
#pragma unroll
          for (int d = 1; d < 16; d <<= 1) {
            s += __shfl_xor(s, d, 64); s2 += __shfl_xor(s2, d, 64);
          }
          if (fm == (mi * 4 + rr)) { lnS[wn * 128 + lrow] = s;
                                     lnS2[wn * 128 + lrow] = s2; }
        }
      barL();
#pragma unroll
      for (int mi = 0; mi < 4; ++mi)
#pragma unroll
        for (int rr = 0; rr < 4; ++rr) {
          int lrow = wm * 64 + mi * 16 + q * 4 + rr;
          float st = lnS[lrow] + lnS[128 + lrow];
          float st2 = lnS2[lrow] + lnS2[128 + lrow];
          float mu = st * (1.f / 128.f);
          float var = fmaxf(st2 * (1.f / 128.f) - mu * mu, 0.f);
          float rstd = rsqrtf(var + 1e-5f);
#pragma unroll
          for (int ni = 0; ni < 4; ++ni) {
            int cl = ni * 16 + fm;
            bufB[wn][lrow * 64 +
                ((((cl >> 3) ^ (lrow & 7)) << 3) | (cl & 7))] =
                (bf16_t)((accA[mi][ni][rr] - mu) * rstd);
          }
        }
      barL();                // X published; lnS (Ws) readers done
      stageWd1(0);           // FFN c0 weights in flight
    }
  }

  // ---- FFN: accA += relu(X @ Wd1_c + bd1_c) @ Wd2_c over 8x64-col chunks.
  // Weights double-buffered: Wd1 in Ws, Wd2 in bufA[1]; counted vmcnt(4),
  // never drained mid-loop.  X in bufB.
  {
    zeroA();
#pragma unroll 1
    for (int c = 0; c < 8; ++c) {
      stageWd2(c);                         // a: Wd2_c -> bufA[1]
      wait_v4_bar();                       // b: Wd1_c resident, publish
      f32x4 accH[4][2] = {};
      __builtin_amdgcn_s_setprio(1);
      mmN<2>(bufB[0],        Ws,        wm, wn, fm, q, fx, accH);
      mmN<2>(bufB[0] + 8192, Ws + 4096, wm, wn, fm, q, fx, accH);
      __builtin_amdgcn_s_setprio(0);
      // bias + relu -> H chunk [128][64] in bufA[0]
#pragma unroll
      for (int mi = 0; mi < 4; ++mi)
#pragma unroll
        for (int rr = 0; rr < 4; ++rr) {
          int row = wm * 64 + mi * 16 + q * 4 + rr;
#pragma unroll
          for (int ni = 0; ni < 2; ++ni) {
            int cH = wn * 32 + ni * 16 + fm;
            float hv = fmaxf(accH[mi][ni][rr] +
                             (float)a.bd1[c * 64 + cH], 0.f);
            bufA[0][row * 64 +
                ((((cH >> 3) ^ (row & 7)) << 3) | (cH & 7))] = (bf16_t)hv;
          }
        }
      barL();                              // c: H visible; Ws readers done
      if (c < 7) {
        stageWd1(c + 1);                   // d: next Wd1 in flight
        asm volatile("s_waitcnt vmcnt(4) lgkmcnt(0)" ::: "memory");  // e
      } else {
        asm volatile("s_waitcnt vmcnt(0) lgkmcnt(0)" ::: "memory");
      }
      __builtin_amdgcn_s_barrier();
      __builtin_amdgcn_sched_barrier(0);
      __builtin_amdgcn_s_setprio(1);
      mmN<4>(bufA[0], bufA[1], wm, wn, fm, q, fx, accA);   // g
      __builtin_amdgcn_s_setprio(0);
      __builtin_amdgcn_sched_barrier(0);
      __builtin_amdgcn_s_barrier();        // h: bufA[1]/bufA[0] readers done
      __builtin_amdgcn_sched_barrier(0);
    }

    // final LN: out = LN(X + accA + bd2) * mvec
    __syncthreads();         // Ws -> lnS reuse safe
#pragma unroll
    for (int mi = 0; mi < 4; ++mi)
#pragma unroll
      for (int rr = 0; rr < 4; ++rr) {
        int lrow = wm * 64 + mi * 16 + q * 4 + rr;
        float s = 0.f, s2 = 0.f;
#pragma unroll
        for (int ni = 0; ni < 4; ++ni) {
          int cl = ni * 16 + fm;
          float xv = (float)bufB[wn][lrow * 64 +
              ((((cl >> 3) ^ (lrow & 7)) << 3) | (cl & 7))];
          float v = accA[mi][ni][rr] + (float)a.bd2[wn * 64 + cl] + xv;
          accA[mi][ni][rr] = v;
          s += v; s2 += v * v;
        }
#pragma unroll
        for (int d = 1; d < 16; d <<= 1) {
          s += __shfl_xor(s, d, 64); s2 += __shfl_xor(s2, d, 64);
        }
        if (fm == (mi * 4 + rr)) { lnS[wn * 128 + lrow] = s;
                                   lnS2[wn * 128 + lrow] = s2; }
      }
    __syncthreads();
#pragma unroll
    for (int mi = 0; mi < 4; ++mi)
#pragma unroll
      for (int rr = 0; rr < 4; ++rr) {
        int lrow = wm * 64 + mi * 16 + q * 4 + rr;
        size_t rg = (size_t)(row0 + lrow);
        float st = lnS[lrow] + lnS[128 + lrow];
        float st2 = lnS2[lrow] + lnS2[128 + lrow];
        float mu = st * (1.f / 128.f);
        float var = fmaxf(st2 * (1.f / 128.f) - mu * mu, 0.f);
        float rstd = rsqrtf(var + 1e-5f);
        float mk = a.mvec[rg];
#pragma unroll
        for (int ni = 0; ni < 4; ++ni) {
          int col = wn * 64 + ni * 16 + fm;
          float ov = (accA[mi][ni][rr] - mu) * rstd * mk;
          a.outF[rg * 128 + col] = (bf16_t)ov;
          if constexpr (MODE == 2) accA[mi][ni][rr] = ov;
        }
      }

    if constexpr (MODE == 2) {
      // emit edge-phase U/G from the fresh hV tile
      __syncthreads();       // all waves done reading X from bufB
      wb(accA, bufB[0]);     // hV_new -> bufB (swizzled)
      zeroA();
      do_gemm(bufB[0], a.Wug, 0, 384, accA);
#pragma unroll
      for (int mi = 0; mi < 4; ++mi)
#pragma unroll
        for (int rr = 0; rr < 4; ++rr) {
          size_t rg = (size_t)(row0 + wm * 64 + mi * 16 + q * 4 + rr);
#pragma unroll
          for (int ni = 0; ni < 4; ++ni) {
            int col = wn * 64 + ni * 16 + fm;
            a.Uo[rg * 128 + col] = accA[mi][ni][rr] + (float)a.bug[col];
          }
        }
      zeroA();
      do_gemm(bufB[0], a.Wug, 256, 384, accA);
#pragma unroll
      for (int mi = 0; mi < 4; ++mi)
#pragma unroll
        for (int rr = 0; rr < 4; ++rr) {
          size_t rg = (size_t)(row0 + wm * 64 + mi * 16 + q * 4 + rr);
#pragma unroll
          for (int ni = 0; ni < 4; ++ni) {
            int col = wn * 64 + ni * 16 + fm;
            a.Go[rg * 128 + col] = accA[mi][ni][rr];
          }
        }
    }
  }
}

// ================= unified 128x128 MFMA GEMM (embeds / node-UG / head) ====
__global__ __launch_bounds__(256) void gk(
    const bf16_t* __restrict__ A, int lda,
    const bf16_t* __restrict__ Bt, int ldb, int koff,
    const bf16_t* __restrict__ bias,
    int N, int K, int epi,
    bf16_t* __restrict__ C,
    float* __restrict__ Cf, float* __restrict__ Cf1, int koff1,
    const float* __restrict__ U, const float* __restrict__ G,
    const int* __restrict__ E_idx,
    bf16_t* __restrict__ resid, const float* __restrict__ mvec, int row0g,
    const int* __restrict__ inv, const int* __restrict__ flag,
    void* __restrict__ outp)
{
  __shared__ __align__(16) bf16_t As[128 * 64];
  __shared__ __align__(16) bf16_t Bs[128 * 64];
  __shared__ float lnS[2][128];
  __shared__ float lnS2[2][128];

  float* CfD = Cf;
  if (epi == EPI_F32 && blockIdx.z == 1) { koff = koff1; bias = nullptr; CfD = Cf1; }

  const int tid = threadIdx.x;
  const int w = tid >> 6, l = tid & 63;
  const int wm = w & 1, wn = w >> 1;
  const int row0 = blockIdx.y * 128;
  const int col0 = blockIdx.x * 128;
  const int lr = l >> 3;
  const int kg8 = ((l & 7) ^ lr) << 3;

  const bf16_t* ap[4];
  const bf16_t* bp[4];
#pragma unroll
  for (int s = 0; s < 4; ++s) {
    int rA = row0 + w * 32 + s * 8 + lr;
    const bf16_t* abase;
    if (epi == EPI_OUT) {
      int bb = rA / NK;
      abase = A + (size_t)(bb * NK + inv[rA]) * lda;
    } else {
      abase = A + (size_t)rA * lda;
    }
    ap[s] = abase + kg8;
    int rB = col0 + w * 32 + s * 8 + lr;
    if (rB >= N) rB = N - 1;
    bp[s] = Bt + (size_t)rB * ldb + koff + kg8;
  }

  const int fm = l & 15, q = l >> 4, fx = fm & 7;
  f32x4 acc[4][4] = {};

  for (int kt = 0; kt < K; kt += 64) {
    __syncthreads();
#pragma unroll
    for (int s = 0; s < 4; ++s)
      gld16(ap[s] + kt, &As[w * 2048 + s * 512]);
#pragma unroll
    for (int s = 0; s < 4; ++s)
      gld16(bp[s] + kt, &Bs[w * 2048 + s * 512]);
    __syncthreads();
#pragma unroll
    for (int h = 0; h < 2; ++h) {
      bf16x8 af[4], bfv[4];
#pragma unroll
      for (int mi = 0; mi < 4; ++mi)
        af[mi] = *reinterpret_cast<const bf16x8*>(
            &As[(wm * 64 + mi * 16 + fm) * 64 + ((((h << 2) | q) ^ fx) << 3)]);
#pragma unroll
      for (int ni = 0; ni < 4; ++ni)
        bfv[ni] = *reinterpret_cast<const bf16x8*>(
            &Bs[(wn * 64 + ni * 16 + fm) * 64 + ((((h << 2) | q) ^ fx) << 3)]);
#pragma unroll
      for (int mi = 0; mi < 4; ++mi)
#pragma unroll
        for (int ni = 0; ni < 4; ++ni)
          acc[mi][ni] = __builtin_amdgcn_mfma_f32_16x16x32_bf16(
              af[mi], bfv[ni], acc[mi][ni], 0, 0, 0);
    }
  }

  if (epi <= EPI_F32) {
#pragma unroll
    for (int ni = 0; ni < 4; ++ni) {
      int col = col0 + wn * 64 + ni * 16 + fm;
      if (col >= N) continue;
      float bv = bias ? (float)bias[col] : 0.f;
#pragma unroll
      for (int mi = 0; mi < 4; ++mi)
#pragma unroll
        for (int rr = 0; rr < 4; ++rr) {
          size_t rg = (size_t)(row0g + row0 + wm * 64 + mi * 16 + q * 4 + rr);
          float v = acc[mi][ni][rr] + bv;
          if (epi == EPI_RELU) v = fmaxf(v, 0.f);
          if (epi == EPI_F32) CfD[rg * N + col] = v;
          else                C[rg * N + col] = (bf16_t)v;
        }
    }
  } else if (epi == EPI_LN) {
#pragma unroll
    for (int mi = 0; mi < 4; ++mi)
#pragma unroll
      for (int rr = 0; rr < 4; ++rr) {
        int lrow = wm * 64 + mi * 16 + q * 4 + rr;
        size_t rg = (size_t)(row0g + row0 + lrow);
        float s = 0.f, s2 = 0.f;
#pragma unroll
        for (int ni = 0; ni < 4; ++ni) {
          int col = wn * 64 + ni * 16 + fm;
          float v = acc[mi][ni][rr] + (bias ? (float)bias[col] : 0.f)
                    + (float)resid[rg * 128 + col];
          acc[mi][ni][rr] = v;
          s += v; s2 += v * v;
        }
#pragma unroll
        for (int d = 1; d < 16; d <<= 1) {
          s += __shfl_xor(s, d, 64); s2 += __shfl_xor(s2, d, 64);
        }
        if (fm == (mi * 4 + rr)) { lnS[wn][lrow] = s; lnS2[wn][lrow] = s2; }
      }
    __syncthreads();
#pragma unroll
    for (int mi = 0; mi < 4; ++mi)
#pragma unroll
      for (int rr = 0; rr < 4; ++rr) {
        int lrow = wm * 64 + mi * 16 + q * 4 + rr;
        size_t rg = (size_t)(row0g + row0 + lrow);
        float st = lnS[0][lrow] + lnS[1][lrow];
        float st2 = lnS2[0][lrow] + lnS2[1][lrow];
        float mu = st * (1.f / 128.f);
        float var = fmaxf(st2 * (1.f / 128.f) - mu * mu, 0.f);
        float rstd = rsqrtf(var + 1e-5f);
        float mk = mvec ? mvec[rg] : 1.f;
#pragma unroll
        for (int ni = 0; ni < 4; ++ni) {
          int col = wn * 64 + ni * 16 + fm;
          resid[rg * 128 + col] = (bf16_t)((acc[mi][ni][rr] - mu) * rstd * mk);
        }
      }
  } else if (epi == EPI_OUT) {
    const int fl = *flag;
#pragma unroll
    for (int ni = 0; ni < 4; ++ni) {
      int col = col0 + wn * 64 + ni * 16 + fm;
      if (col >= ODIM_) continue;
      float bv = bias ? (float)bias[col] : 0.f;
#pragma unroll
      for (int mi = 0; mi < 4; ++mi)
#pragma unroll
        for (int rr = 0; rr < 4; ++rr) {
          size_t rg = (size_t)(row0 + wm * 64 + mi * 16 + q * 4 + rr);
          float v = acc[mi][ni][rr] + bv;
          size_t idx = rg * ODIM_ + col;
          if (fl) ((bf16_t*)outp)[idx] = (bf16_t)v;
          else    ((float*)outp)[idx]  = v;
        }
    }
  }
}

// ================= dtype sniff =================
__global__ void flag_kernel(const uint32_t* __restrict__ xm_raw,
                            int* __restrict__ flag)
{
  if (threadIdx.x == 0 && blockIdx.x == 0)
    *flag = (xm_raw[0] == 0x3F803F80u) ? 1 : 0;
}

// ================= fused convert (+ weight transpose) =================
struct ConvSeg { const void* src; void* dst; int n; int K; int N; };
struct ConvArgs { ConvSeg s[29]; };

__global__ __launch_bounds__(256) void conv_kernel(
    ConvArgs a, int nseg, int total8, const int* __restrict__ flag)
{
  int t = blockIdx.x * 256 + threadIdx.x;
  if (t >= total8) return;
  const int fl = *flag;
  int seg = 0, t8 = t;
  while (seg < nseg - 1 && t8 >= (a.s[seg].n >> 3)) { t8 -= a.s[seg].n >> 3; ++seg; }
  const ConvSeg sg = a.s[seg];
  const int e = t8 << 3;
  float vals[8];
  if (fl) {
    union { uint4 v; bf16_t b[8]; } u;
    u.v = *((const uint4*)sg.src + t8);
#pragma unroll
    for (int j = 0; j < 8; ++j) vals[j] = (float)u.b[j];
  } else {
    const float* sp = (const float*)sg.src + e;
#pragma unroll
    for (int j = 0; j < 8; ++j) vals[j] = sp[j];
  }
  if (sg.N == 0) {
    union { uint4 v; bf16_t b[8]; } o;
#pragma unroll
    for (int j = 0; j < 8; ++j) o.b[j] = (bf16_t)vals[j];
    *((uint4*)sg.dst + t8) = o.v;
  } else {
    const int KN_ = sg.K * sg.N;
    const int lay = e / KN_;
    const int rem = e - lay * KN_;
    const int k = rem / sg.N;
    const int n0 = rem - k * sg.N;
    bf16_t* dp = (bf16_t*)sg.dst + (size_t)lay * KN_ + k;
#pragma unroll
    for (int j = 0; j < 8; ++j)
      dp[(size_t)(n0 + j) * sg.K] = (bf16_t)vals[j];
  }
}

// ================= mask_attend (+ float x_mask side copy) =================
__global__ __launch_bounds__(256) void mask_kernel(
    const bf16_t* __restrict__ xm, const int* __restrict__ E_idx,
    float* __restrict__ ma, float* __restrict__ xmf)
{
  int r = blockIdx.x * 256 + threadIdx.x;
  if (r >= RT) return;
  if (r < BN_) xmf[r] = (float)xm[r];
  int b = r / NK;
  int n = (r / KN) % N_;
  ma[r] = (float)xm[b * N_ + E_idx[r]] * (float)xm[b * N_ + n];
}

// ================= zero + node LN =================
__global__ __launch_bounds__(256) void zero_kernel(float* __restrict__ p, int n)
{
  int i = blockIdx.x * 256 + threadIdx.x;
  if (i < n) p[i] = 0.f;
}

__global__ __launch_bounds__(128) void node_ln_kernel(
    float* __restrict__ Agg, bf16_t* __restrict__ hV)
{
  int bn = blockIdx.x;
  int c = threadIdx.x;
  size_t idx = (size_t)bn * H_ + c;
  float v = (float)hV[idx] + Agg[idx] * (1.0f / 30.0f);
  Agg[idx] = 0.f;               // re-arm accumulator for next layer
  __shared__ float red[4];
  float ss = wred(v), s2 = wred(v * v);
  int w = c >> 6, lane = c & 63;
  if (lane == 0) { red[w * 2] = ss; red[w * 2 + 1] = s2; }
  __syncthreads();
  float tot = red[0] + red[2], tot2 = red[1] + red[3];
  float mu = tot * (1.f / 128.f);
  float var = fmaxf(tot2 * (1.f / 128.f) - mu * mu, 0.f);
  float rstd = rsqrtf(var + 1e-5f);
  hV[idx] = (bf16_t)((v - mu) * rstd);
}

// ================= launch =================
extern "C" void kernel_launch(void* const* d_in, const int* in_sizes, int n_in,
                              void* d_out, int out_size, void* d_ws, size_t ws_size,
                              hipStream_t stream)
{
  const int* E_idx  = (const int*)d_in[2];
  const int* invmap = (const int*)d_in[3];

  char* ws = (char*)d_ws;
  size_t woff = 0;
  auto walloc = [&](size_t bytes) -> char* {
    char* p = ws + woff; woff += (bytes + 255) & ~(size_t)255; return p;
  };
  int*    flag  = (int*)walloc(4);
  bf16_t* WtOut = (bf16_t*)walloc((size_t)51200 * 2);
  bf16_t* outbc = (bf16_t*)walloc((size_t)400 * 2);
  bf16_t* hE    = (bf16_t*)walloc((size_t)RT * H_ * 2);

  char* ob = (char*)d_out;
  bf16_t* t0 = (bf16_t*)ob;
  bf16_t* t1 = (bf16_t*)(ob + (size_t)RT * H_ * 2);
  size_t ooff = (size_t)RT * H_ * 2 * 2;
  auto oalloc = [&](size_t bytes) -> char* {
    char* p = ob + ooff; ooff += (bytes + 255) & ~(size_t)255; return p;
  };
  bf16_t* WtV  = (bf16_t*)oalloc(16384 * 2);
  bf16_t* bvc  = (bf16_t*)oalloc(128 * 2);
  bf16_t* WtE  = (bf16_t*)oalloc(16384 * 2);
  bf16_t* bec  = (bf16_t*)oalloc(128 * 2);
  bf16_t* Wtn1 = (bf16_t*)oalloc((size_t)147456 * 2);
  bf16_t* nb1c = (bf16_t*)oalloc(384 * 2);
  bf16_t* Wtn2 = (bf16_t*)oalloc((size_t)49152 * 2);
  bf16_t* nb2c = (bf16_t*)oalloc(384 * 2);
  bf16_t* Wtn3 = (bf16_t*)oalloc((size_t)49152 * 2);
  bf16_t* nb3c = (bf16_t*)oalloc(384 * 2);
  bf16_t* Wtnd1 = (bf16_t*)oalloc((size_t)196608 * 2);
  bf16_t* nbd1c = (bf16_t*)oalloc(1536 * 2);
  bf16_t* Wtnd2 = (bf16_t*)oalloc((size_t)196608 * 2);
  bf16_t* nbd2c = (bf16_t*)oalloc(384 * 2);
  bf16_t* Wte1 = (bf16_t*)oalloc((size_t)147456 * 2);
  bf16_t* eb1c = (bf16_t*)oalloc(384 * 2);
  bf16_t* Wte2 = (bf16_t*)oalloc((size_t)49152 * 2);
  bf16_t* eb2c = (bf16_t*)oalloc(384 * 2);
  bf16_t* Wte3 = (bf16_t*)oalloc((size_t)49152 * 2);
  bf16_t* eb3c = (bf16_t*)oalloc(384 * 2);
  bf16_t* Wted1 = (bf16_t*)oalloc((size_t)196608 * 2);
  bf16_t* ebd1c = (bf16_t*)oalloc(1536 * 2);
  bf16_t* Wted2 = (bf16_t*)oalloc((size_t)196608 * 2);
  bf16_t* ebd2c = (bf16_t*)oalloc(384 * 2);
  float*  Ubuf = (float*)oalloc((size_t)BN_ * 128 * 4);
  float*  Gbuf = (float*)oalloc((size_t)BN_ * 128 * 4);
  bf16_t* hV   = (bf16_t*)oalloc((size_t)BN_ * 128 * 2);
  float*  ma   = (float*)oalloc((size_t)RT * 4);
  bf16_t* xm   = (bf16_t*)oalloc((size_t)BN_ * 2);
  float*  xmf  = (float*)oalloc((size_t)BN_ * 4);
  float*  Abuf = (float*)oalloc((size_t)BN_ * 128 * 4);   // node agg (1 MB)

  ConvArgs ca;
  struct D { int idx; void* dst; int K; int N; };
  const D dl[29] = {
    {0, t1, 0, 0}, {1, t0, 0, 0}, {4, xm, 0, 0},
    {5, WtV, 128, 128}, {6, bvc, 0, 0}, {7, WtE, 128, 128}, {8, bec, 0, 0},
    {9, Wtn1, 384, 128}, {10, nb1c, 0, 0}, {11, Wtn2, 128, 128}, {12, nb2c, 0, 0},
    {13, Wtn3, 128, 128}, {14, nb3c, 0, 0},
    {15, Wtnd1, 128, 512}, {16, nbd1c, 0, 0}, {17, Wtnd2, 512, 128}, {18, nbd2c, 0, 0},
    {19, Wte1, 384, 128}, {20, eb1c, 0, 0}, {21, Wte2, 128, 128}, {22, eb2c, 0, 0},
    {23, Wte3, 128, 128}, {24, eb3c, 0, 0},
    {25, Wted1, 128, 512}, {26, ebd1c, 0, 0}, {27, Wted2, 512, 128}, {28, ebd2c, 0, 0},
    {29, WtOut, 128, 400}, {30, outbc, 0, 0}
  };
  int total8 = 0;
  for (int i = 0; i < 29; ++i) {
    ca.s[i].src = d_in[dl[i].idx];
    ca.s[i].dst = dl[i].dst;
    ca.s[i].n   = in_sizes[dl[i].idx];
    ca.s[i].K   = dl[i].K;
    ca.s[i].N   = dl[i].N;
    total8 += ca.s[i].n >> 3;
  }

  auto g = [&](dim3 grid, const bf16_t* A, int lda, const bf16_t* Bt, int ldb,
               int koff, const bf16_t* bias, int N, int K, int epi,
               bf16_t* C, float* Cf, float* Cf1, int koff1,
               bf16_t* resid, const float* mvec, int row0g) {
    gk<<<grid, 256, 0, stream>>>(A, lda, Bt, ldb, koff, bias, N, K, epi,
        C, Cf, Cf1, koff1, Ubuf, Gbuf, E_idx, resid, mvec, row0g,
        invmap, flag, d_out);
  };
  const float* NOM = nullptr;

  flag_kernel<<<1, 64, 0, stream>>>((const uint32_t*)d_in[4], flag);
  conv_kernel<<<(total8 + 255) / 256, 256, 0, stream>>>(ca, 29, total8, flag);
  mask_kernel<<<RT / 256, 256, 0, stream>>>(xm, E_idx, ma, xmf);
  zero_kernel<<<(BN_ * 128) / 256, 256, 0, stream>>>(Abuf, BN_ * 128);

  // embeds
  g(dim3(1, BN_ / 128), t1, 128, WtV, 128, 0, bvc, 128, 128, EPI_PLAIN,
    hV, nullptr, nullptr, 0, nullptr, NOM, 0);
  g(dim3(1, RT / 128), t0, 128, WtE, 128, 0, bec, 128, 128, EPI_PLAIN,
    hE, nullptr, nullptr, 0, nullptr, NOM, 0);

  for (int l = 0; l < L_; ++l) {
    // ---- node U/G from hV ----
    g(dim3(1, BN_ / 128, 2), hV, 128, Wtn1 + (size_t)l * 49152, 384, 0,
      nb1c + l * 128, 128, 128, EPI_F32,
      nullptr, Ubuf, Gbuf, 128, nullptr, NOM, 0);
    // ---- node message + aggregation ----
    {
      GCArgs na{};
      na.Ain = hE;
      na.W1 = Wtn1 + (size_t)l * 49152; na.koff1 = 256; na.ldw1 = 384;
      na.W2 = Wtn2 + (size_t)l * 16384; na.b2 = nb2c + l * 128;
      na.W3 = Wtn3 + (size_t)l * 16384; na.b3 = nb3c + l * 128;
      na.U = Ubuf; na.G = Gbuf; na.E = E_idx;
      na.ma = ma; na.Agg = Abuf;
      gc<0><<<RT / 128, 256, 0, stream>>>(na);
    }
    node_ln_kernel<<<BN_, 128, 0, stream>>>(Abuf, hV);
    // ---- node FFN + edge U/G emit ----
    {
      GCArgs nf{};
      nf.Ain = hV;
      nf.Wd1 = Wtnd1 + (size_t)l * 65536; nf.bd1 = nbd1c + l * 512;
      nf.Wd2 = Wtnd2 + (size_t)l * 65536; nf.bd2 = nbd2c + l * 128;
      nf.mvec = xmf; nf.outF = hV;
      nf.Wug = Wte1 + (size_t)l * 49152; nf.bug = eb1c + l * 128;
      nf.Uo = Ubuf; nf.Go = Gbuf;
      gc<2><<<BN_ / 128, 256, 0, stream>>>(nf);
    }
    // ---- edge update (fully fused) ----
    {
      GCArgs ea{};
      ea.Ain = hE;
      ea.W1 = Wte1 + (size_t)l * 49152; ea.koff1 = 128; ea.ldw1 = 384;
      ea.W2 = Wte2 + (size_t)l * 16384; ea.b2 = eb2c + l * 128;
      ea.W3 = Wte3 + (size_t)l * 16384; ea.b3 = eb3c + l * 128;
      ea.U = Ubuf; ea.G = Gbuf; ea.E = E_idx;
      ea.Wd1 = Wted1 + (size_t)l * 65536; ea.bd1 = ebd1c + l * 512;
      ea.Wd2 = Wted2 + (size_t)l * 65536; ea.bd2 = ebd2c + l * 128;
      ea.mvec = ma; ea.outF = hE;
      gc<1><<<RT / 128, 256, 0, stream>>>(ea);
    }
  }

  // output head: fused merge_dups gather, dtype-aware store
  g(dim3(4, RT / 128), hE, 128, WtOut, 128, 0, outbc, ODIM_, 128, EPI_OUT,
    nullptr, nullptr, nullptr, 0, nullptr, NOM, 0);
}